// Round 5
// baseline (505.194 us; speedup 1.0000x reference)
//
#include <hip/hip_runtime.h>
#include <hip/hip_bf16.h>
#include <stdint.h>

// DecoderSelfAttention: B=8, S=2048, D=1024 (d_k=d_v=d_model)
// Pipeline (all bf16 MFMA, fp32 accumulate), 5 dispatches:
//   prep:    x->bf16, W->W^T bf16
//   qkproj:  [Q|K] = x@[Wq|Wk]      (256^2 reg-pipelined core v5)
//   vproj:   V^T = Wv^T@x^T         (256^2 reg-pipelined core v5)
//   qk_p:    P' = exp(QK^T/32) causal tiles + row-sum partials  (XCD==batch)
//   pv:      out = (P' @ V) * 1/rowsum                          (XCD==batch)
//
// mm256_core v5 == v4 schedule with the VGPR cap removed.
// r4 lesson: __launch_bounds__(512,2) caps VGPR at 128; v4's live set
// (acc 128 + frag dbuf 80 + addressing) ~230 -> compiler spilled the frag
// double-buffer to scratch (WRITE_SIZE 66->164MB, FETCH 49->97MB, 183us).
// v5: __launch_bounds__(512,1). Occupancy unchanged (LDS 128KiB -> 1
// block/CU either way); only the artificial reg ceiling goes away.
//
// Schedule (v4): 256x256 tile, BK=32, 512 thr (8 waves 2Mx4N, 128x64/wave).
// Ring-4 K-tile buffers as EIGHT DISTINCT __shared__ arrays (alias-clean, r3:
// backend can't re-insert vmcnt drains), loop unrolled x4 -> compile-time
// slots. Register-level fragment double-buffer + ONE barrier/tile.
// Body T computes tile T entirely from regs prefetched at body T-1; reads for
// tile T+1 are issued fire-and-forget and gated by counted lgkmcnt:
//   stage(T+2); vmcnt(4); BAR;
//   read a1_T (cur slot, 4) + a0/bv_{T+1} (nxt slot, 8);
//   lgkmcnt(12) -> a0/bv_T (issued last body) complete; 16 MFMA (c1);
//   lgkmcnt(8)  -> a1_T complete;                       16 MFMA (c2).
// Race proof (1 barrier/tile, 2-ahead staging, ring-4):
//   RAW: reads(T+1) after BAR(T); every wave passed vmcnt(4) (drains its
//        stage(T+1) DMA) before BAR(T) -> tile T+1 fully in LDS.
//   WAR: stage(T+2) (after BAR(T-1)) overwrites slot (T+2)&3, last read as
//        tile T-2 frags; those reads retired at each wave's lgkmcnt in body
//        T-2, which precedes BAR(T-1) in program order.
//   In-flight DMA after vmcnt(4) = stage(T+2) only; reads touch slots T&3,
//        (T+1)&3 -> disjoint.
// Frag sets P/Q alternate via x4-unrolled loop (named regs, rule #20).
// Swizzle (verified conflict-free r1-r3): stored 16B-unit c at row holds
// global unit c^((row>>1)&3); reader key ((fm>>1)&3).

typedef __bf16 bf16_t;
typedef __bf16 bf16x4 __attribute__((ext_vector_type(4)));
typedef __bf16 bf16x8 __attribute__((ext_vector_type(8)));
typedef float  floatx4 __attribute__((ext_vector_type(4)));

#define NB 8
#define SS 2048
#define DD 1024
#define INV_SCALE 0.03125f   // 1/sqrt(1024)

__device__ __forceinline__ void async_ld16(const void* g, void* l) {
  __builtin_amdgcn_global_load_lds(
      (const __attribute__((address_space(1))) void*)g,
      (__attribute__((address_space(3))) void*)l, 16, 0, 0);
}

#define BARRIER() do { asm volatile("" ::: "memory"); \
  __builtin_amdgcn_s_barrier(); asm volatile("" ::: "memory"); } while (0)

// ---------------- 256x256 reg-pipelined GEMM core v5 ----------------
// C = A * B^T, A[M,K] row-major, B[N,K] row-major, both bf16, BK=32.
// nt = number of 32-wide K steps; REQUIRES nt % 4 == 0, nt >= 4.
__device__ __forceinline__ void mm256_core(
    const bf16_t* __restrict__ Ab, const bf16_t* __restrict__ Bb,
    int lda, int ldb, int nt,
    bf16_t* sA0, bf16_t* sA1, bf16_t* sA2, bf16_t* sA3,
    bf16_t* sB0, bf16_t* sB1, bf16_t* sB2, bf16_t* sB3,
    floatx4 acc[8][4]) {
  const int t    = threadIdx.x;         // 0..511
  const int lane = t & 63;
  const int wid  = t >> 6;
  const int wm   = wid >> 2;            // 0..1
  const int wn   = wid & 3;             // 0..3
  const int fm   = lane & 15;
  const int q    = lane >> 4;           // 0..3 (k-group)
  const int co   = (q ^ ((fm >> 1) & 3)) * 8;   // swizzled k-group offset

  // staging: 2 units/thread/operand; unit u: row=u>>2, src group=(u&3)^((row>>1)&3)
  size_t goA[2], goB[2]; int lo[2];
#pragma unroll
  for (int k = 0; k < 2; ++k) {
    const int u   = k * 512 + t;
    const int row = u >> 2;
    const int cg  = (u & 3) ^ ((row >> 1) & 3);
    goA[k] = (size_t)row * lda + cg * 8;
    goB[k] = (size_t)row * ldb + cg * 8;
    lo[k]  = u * 8;
  }

  auto stage = [&](bf16_t* la, bf16_t* lb, int tile) {
    const size_t ko = (size_t)tile * 32;
    async_ld16(Ab + ko + goA[0], la + lo[0]);
    async_ld16(Ab + ko + goA[1], la + lo[1]);
    async_ld16(Bb + ko + goB[0], lb + lo[0]);
    async_ld16(Bb + ko + goB[1], lb + lo[1]);
  };

  const int paOff = (wm * 128 + fm) * 32;
  const int pbOff = (wn * 64 + fm) * 32;

  // fragment register sets: P/Q double-buffer for a0/bv; aT transient per body
  bf16x8 a0P[4], bvP[4], a0Q[4], bvQ[4], aT[4];

  // prologue: stage tiles 0,1; drain tile 0; read tile-0 a0/bv into set P
  stage(sA0, sB0, 0);
  stage(sA1, sB1, 1);
  asm volatile("s_waitcnt vmcnt(4)" ::: "memory");   // tile 0 landed (mine)
  BARRIER();                                          // ...everyone's
  {
    const bf16_t* pa = sA0 + paOff;
    const bf16_t* pb = sB0 + pbOff;
#pragma unroll
    for (int i = 0; i < 4; ++i) a0P[i] = *(const bf16x8*)(pa + i * 512 + co);
#pragma unroll
    for (int j = 0; j < 4; ++j) bvP[j] = *(const bf16x8*)(pb + j * 512 + co);
  }

  // body T: compute tile T from (ca0,cbv) [+ aT read here], prefetch
  // (na0,nbv) of tile T+1 from (NAp,NBp); stage tile T+2 into (SAp,SBp).
  auto body = [&] __attribute__((always_inline)) (
      const bf16_t* CAp, const bf16_t* NAp, const bf16_t* NBp,
      bf16_t* SAp, bf16_t* SBp,
      bf16x8 (&ca0)[4], bf16x8 (&cbv)[4],
      bf16x8 (&na0)[4], bf16x8 (&nbv)[4], int T) {
    if (T + 2 < nt) {
      stage(SAp, SBp, T + 2);
      asm volatile("s_waitcnt vmcnt(4)" ::: "memory");   // tile T+1 landed
    } else if (T + 1 < nt) {
      asm volatile("s_waitcnt vmcnt(0)" ::: "memory");
    }
    BARRIER();

    // a1 of tile T (cur slot, rows 4..7) — fire-and-forget
    const bf16_t* pac = CAp + paOff;
#pragma unroll
    for (int i = 0; i < 4; ++i) aT[i] = *(const bf16x8*)(pac + (4 + i) * 512 + co);
    if (T + 1 < nt) {
      // a0/bv of tile T+1 — fire-and-forget
      const bf16_t* pan = NAp + paOff;
      const bf16_t* pbn = NBp + pbOff;
#pragma unroll
      for (int i = 0; i < 4; ++i) na0[i] = *(const bf16x8*)(pan + i * 512 + co);
#pragma unroll
      for (int j = 0; j < 4; ++j) nbv[j] = *(const bf16x8*)(pbn + j * 512 + co);
      asm volatile("s_waitcnt lgkmcnt(12)" ::: "memory"); // ca0/cbv complete
    } else {
      asm volatile("s_waitcnt lgkmcnt(4)" ::: "memory");  // ca0/cbv complete
    }
    __builtin_amdgcn_sched_barrier(0);
    __builtin_amdgcn_s_setprio(1);
#pragma unroll
    for (int i = 0; i < 4; ++i)
#pragma unroll
      for (int j = 0; j < 4; ++j)
        acc[i][j] = __builtin_amdgcn_mfma_f32_16x16x32_bf16(cbv[j], ca0[i], acc[i][j], 0, 0, 0);
    __builtin_amdgcn_s_setprio(0);

    if (T + 1 < nt) {
      asm volatile("s_waitcnt lgkmcnt(8)" ::: "memory");  // aT complete
    } else {
      asm volatile("s_waitcnt lgkmcnt(0)" ::: "memory");
    }
    __builtin_amdgcn_sched_barrier(0);
    __builtin_amdgcn_s_setprio(1);
#pragma unroll
    for (int i = 0; i < 4; ++i)
#pragma unroll
      for (int j = 0; j < 4; ++j)
        acc[4 + i][j] = __builtin_amdgcn_mfma_f32_16x16x32_bf16(cbv[j], aT[i], acc[4 + i][j], 0, 0, 0);
    __builtin_amdgcn_s_setprio(0);
  };

  for (int T = 0; T < nt; T += 4) {
    //      cur slot  nxt slot      stage slot    cur regs    nxt regs
    body(sA0,  sA1, sB1,  sA2, sB2,  a0P, bvP,  a0Q, bvQ, T + 0);
    body(sA1,  sA2, sB2,  sA3, sB3,  a0Q, bvQ,  a0P, bvP, T + 1);
    body(sA2,  sA3, sB3,  sA0, sB0,  a0P, bvP,  a0Q, bvQ, T + 2);
    body(sA3,  sA0, sB0,  sA1, sB1,  a0Q, bvQ,  a0P, bvP, T + 3);
  }
}

__device__ __forceinline__ void zero_acc8(floatx4 acc[8][4]) {
#pragma unroll
  for (int i = 0; i < 8; ++i)
#pragma unroll
    for (int j = 0; j < 4; ++j)
      acc[i][j] = floatx4{0.f, 0.f, 0.f, 0.f};
}

__device__ __forceinline__ void store_c256_bf16(bf16_t* __restrict__ Cb, int ldc,
                                                floatx4 acc[8][4]) {
  const int lane = threadIdx.x & 63;
  const int wid  = threadIdx.x >> 6;
  const int wm = wid >> 2, wn = wid & 3;
  const int m0 = wm * 128 + (lane & 15);
  const int n0 = wn * 64 + (lane >> 4) * 4;
#pragma unroll
  for (int i = 0; i < 8; ++i)
#pragma unroll
    for (int j = 0; j < 4; ++j) {
      floatx4 a = acc[i][j];
      bf16x4 o = {(bf16_t)a[0], (bf16_t)a[1], (bf16_t)a[2], (bf16_t)a[3]};
      *(bf16x4*)(Cb + (size_t)(m0 + i * 16) * ldc + n0 + j * 16) = o;
    }
}

#define MM256_LDS_DECL                                                      \
  __shared__ __attribute__((aligned(16))) bf16_t sA0[8192], sA1[8192],      \
      sA2[8192], sA3[8192];                                                 \
  __shared__ __attribute__((aligned(16))) bf16_t sB0[8192], sB1[8192],      \
      sB2[8192], sB3[8192];

// ---------------- 128x128 tile GEMM core (legacy, qk_p / pv) ----------------
__device__ __forceinline__ void mm_core(const bf16_t* __restrict__ Ab,
                                        const bf16_t* __restrict__ Bb,
                                        int lda, int ldb, int kTiles,
                                        bf16_t* sA, bf16_t* sB,
                                        floatx4 acc[4][4]) {
  const int t    = threadIdx.x;
  const int lane = t & 63;
  const int wm   = (t >> 6) >> 1;
  const int wn   = (t >> 6) & 1;
  const int fm   = lane & 15;
  const int q    = lane >> 4;       // 0..3
  const int xo   = fm & 7;          // per-lane XOR swizzle key

  const bf16_t* ga[4]; const bf16_t* gb[4];
  bf16_t* la[4]; bf16_t* lb[4];
#pragma unroll
  for (int k = 0; k < 4; ++k) {
    const int u   = k * 256 + t;
    const int row = u >> 3;
    const int cc  = (u & 7) ^ (row & 7);
    ga[k] = Ab + (size_t)row * lda + cc * 8;
    gb[k] = Bb + (size_t)row * ldb + cc * 8;
    la[k] = sA + u * 8;
    lb[k] = sB + u * 8;
  }

  const bf16_t* pa = sA + (wm * 64 + fm) * 64;
  const bf16_t* pb = sB + (wn * 64 + fm) * 64;

  for (int kt = 0; kt < kTiles; ++kt) {
    const int ko = kt * 64;
#pragma unroll
    for (int k = 0; k < 4; ++k) async_ld16(ga[k] + ko, la[k]);
#pragma unroll
    for (int k = 0; k < 4; ++k) async_ld16(gb[k] + ko, lb[k]);
    __syncthreads();
#pragma unroll
    for (int h = 0; h < 2; ++h) {
      const int co = ((h * 4 + q) ^ xo) * 8;
      bf16x8 af[4], bfr[4];
#pragma unroll
      for (int i = 0; i < 4; ++i) af[i]  = *(const bf16x8*)(pa + i * 1024 + co);
#pragma unroll
      for (int j = 0; j < 4; ++j) bfr[j] = *(const bf16x8*)(pb + j * 1024 + co);
#pragma unroll
      for (int i = 0; i < 4; ++i)
#pragma unroll
        for (int j = 0; j < 4; ++j)
          acc[i][j] = __builtin_amdgcn_mfma_f32_16x16x32_bf16(bfr[j], af[i], acc[i][j], 0, 0, 0);
    }
    __syncthreads();
  }
}

__device__ __forceinline__ void zero_acc(floatx4 acc[4][4]) {
#pragma unroll
  for (int i = 0; i < 4; ++i)
#pragma unroll
    for (int j = 0; j < 4; ++j)
      acc[i][j] = floatx4{0.f, 0.f, 0.f, 0.f};
}

// ---------------- fused converters: x->bf16 and W->W^T bf16 ----------------

__global__ __launch_bounds__(256) void prep(const float* __restrict__ x,
                                            const float* __restrict__ Wq,
                                            const float* __restrict__ Wk,
                                            const float* __restrict__ Wv,
                                            bf16_t* __restrict__ xb,
                                            bf16_t* __restrict__ Wt) {
  __shared__ float tile[32][33];
  const int bid = blockIdx.x;
  const int t = threadIdx.x;
  if (bid < 16384) {
    size_t i = (size_t)bid * 256 + t;
    float4 v = ((const float4*)x)[i];
    bf16x4 o = {(bf16_t)v.x, (bf16_t)v.y, (bf16_t)v.z, (bf16_t)v.w};
    ((bf16x4*)xb)[i] = o;
  } else {
    const int wb = bid - 16384;
    const int z = wb >> 10;                 // 0,1,2 -> Wq,Wk,Wv
    const int rem = wb & 1023;
    const float* W = (z == 0) ? Wq : (z == 1 ? Wk : Wv);
    bf16_t* O = Wt + (size_t)z * DD * DD;
    const int ty = t >> 3;
    const int tx = t & 7;
    const int k0 = (rem >> 5) * 32, n0 = (rem & 31) * 32;
    float4 v = *(const float4*)(W + (size_t)(k0 + ty) * DD + n0 + tx * 4);
    tile[ty][tx * 4 + 0] = v.x;
    tile[ty][tx * 4 + 1] = v.y;
    tile[ty][tx * 4 + 2] = v.z;
    tile[ty][tx * 4 + 3] = v.w;
    __syncthreads();
    bf16x4 o = {(bf16_t)tile[tx * 4 + 0][ty], (bf16_t)tile[tx * 4 + 1][ty],
                (bf16_t)tile[tx * 4 + 2][ty], (bf16_t)tile[tx * 4 + 3][ty]};
    *(bf16x4*)(O + (size_t)(n0 + ty) * DD + k0 + tx * 4) = o;
  }
}

// ---------------- QK projection: [Q|K] = x @ [Wq|Wk] ----------------

__global__ __launch_bounds__(512, 1) void qkproj_gemm(
    const bf16_t* __restrict__ xb, const bf16_t* __restrict__ Wt,
    bf16_t* __restrict__ QKb) {
  MM256_LDS_DECL
  const int mt = blockIdx.x, nt = blockIdx.y;
  const bf16_t* Ab = xb + (size_t)mt * 256 * DD;
  const bf16_t* Bb = Wt + (size_t)nt * 256 * DD;
  bf16_t* Cb = QKb + (size_t)mt * 256 * (2 * DD) + nt * 256;
  floatx4 acc[8][4];
  zero_acc8(acc);
  mm256_core(Ab, Bb, DD, DD, DD / 32,
             sA0, sA1, sA2, sA3, sB0, sB1, sB2, sB3, acc);
  store_c256_bf16(Cb, 2 * DD, acc);
}

// ---------------- V projection: V^T[b] = Wv^T @ x[b]^T ----------------
// 1D grid 256: n = bid&7 (XCD), m = (bid>>3)&3, b = bid>>5. 1 block/CU.

__global__ __launch_bounds__(512, 1) void vproj_gemm(
    const bf16_t* __restrict__ xb, const bf16_t* __restrict__ Wt,
    bf16_t* __restrict__ VtB) {
  MM256_LDS_DECL
  const int bid = blockIdx.x;
  const int n = bid & 7;            // seq tile (256 rows)
  const int m = (bid >> 3) & 3;     // dv tile (256 rows)
  const int b = bid >> 5;           // batch
  const bf16_t* Ab = Wt + (size_t)2 * DD * DD + (size_t)m * 256 * DD;
  const bf16_t* Bb = xb + (size_t)b * SS * DD + (size_t)n * 256 * DD;
  bf16_t* Cb = VtB + (size_t)b * DD * SS + (size_t)m * 256 * SS + n * 256;
  floatx4 acc[8][4];
  zero_acc8(acc);
  mm256_core(Ab, Bb, DD, DD, DD / 32,
             sA0, sA1, sA2, sA3, sB0, sB1, sB2, sB3, acc);
  store_c256_bf16(Cb, SS, acc);
}

// ---------------- QK^T -> P' = exp(s) bf16 (causal tiles only) + row-sum partials ----------------
// 1D grid 1088: b = bid&7 (XCD==batch), tt = 135-(bid>>3) (qi descending).

__global__ __launch_bounds__(256) void qk_p(
    const bf16_t* __restrict__ Q, const bf16_t* __restrict__ K,
    bf16_t* __restrict__ P, float* __restrict__ lpart) {
  const int b  = blockIdx.x & 7;
  const int tt = 135 - (blockIdx.x >> 3);
  int qi = (int)((sqrtf(8.0f * tt + 1.0f) - 1.0f) * 0.5f);
  while ((qi + 1) * (qi + 2) / 2 <= tt) ++qi;
  while (qi * (qi + 1) / 2 > tt) --qi;
  const int ki = tt - qi * (qi + 1) / 2;

  __shared__ __attribute__((aligned(16))) bf16_t sA[128 * 64];
  __shared__ __attribute__((aligned(16))) bf16_t sB[128 * 64];
  __shared__ float reds[2][128];
  const bf16_t* Ab = Q + ((size_t)b * SS + qi * 128) * (size_t)(2 * DD);
  const bf16_t* Bb = K + ((size_t)b * SS + ki * 128) * (size_t)(2 * DD);
  floatx4 acc[4][4];
  zero_acc(acc);
  mm_core(Ab, Bb, 2 * DD, 2 * DD, DD / 64, sA, sB, acc);

  const int lane = threadIdx.x & 63;
  const int wm = (threadIdx.x >> 6) >> 1, wn = (threadIdx.x >> 6) & 1;
  const bool diag = (ki == qi);
  bf16_t* Pb = P + (size_t)b * SS * SS;
  const int qloc0 = wm * 64 + (lane & 15);        // + i*16
  const int kvb0  = wn * 64 + (lane >> 4) * 4;    // + j*16, + reg

#pragma unroll
  for (int i = 0; i < 4; ++i) {
    const int qrow = qloc0 + i * 16;
    float partial = 0.f;
#pragma unroll
    for (int j = 0; j < 4; ++j) {
      const int kvb = kvb0 + j * 16;
      floatx4 p;
#pragma unroll
      for (int r = 0; r < 4; ++r) {
        const float s = acc[i][j][r] * INV_SCALE;
        p[r] = (diag && (kvb + r) > qrow) ? 0.f : __expf(s);
        partial += p[r];
      }
      bf16x4 o = {(bf16_t)p[0], (bf16_t)p[1], (bf16_t)p[2], (bf16_t)p[3]};
      *(bf16x4*)(Pb + (size_t)(qi * 128 + qrow) * SS + ki * 128 + kvb) = o;
    }
    partial += __shfl_xor(partial, 16);
    partial += __shfl_xor(partial, 32);
    if ((lane >> 4) == 0) reds[wn][qrow] = partial;
  }
  __syncthreads();
  const int t = threadIdx.x;
  if (t < 128) {
    size_t row = (size_t)b * SS + qi * 128 + t;
    lpart[row * 16 + ki] = reds[0][t] + reds[1][t];
  }
}

// ---------------- PV GEMM (causal-truncated K-loop), rowsum+scale folded, fp32 out ----------------
// 1D grid 1024: b = bid&7 (XCD==batch), nj = (bid>>3)&7, qi = 15-(bid>>6) desc.

__global__ __launch_bounds__(256) void pv_gemm(
    const bf16_t* __restrict__ P, const bf16_t* __restrict__ Vt,
    const float* __restrict__ lpart, float* __restrict__ Out) {
  const int bid = blockIdx.x;
  const int b  = bid & 7;
  const int nj = (bid >> 3) & 7;
  const int qi = 15 - (bid >> 6);

  __shared__ __attribute__((aligned(16))) bf16_t sA[128 * 64];
  __shared__ __attribute__((aligned(16))) bf16_t sB[128 * 64];
  __shared__ float sRl[128];
  const int t = threadIdx.x;
  if (t < 128) {
    const float* lp = lpart + ((size_t)b * SS + qi * 128 + t) * 16;
    float L = 0.f;
    for (int ci = 0; ci <= qi; ++ci) L += lp[ci];
    sRl[t] = 1.0f / L;
  }
  const bf16_t* Ab = P + (size_t)b * SS * SS + (size_t)qi * 128 * SS;
  const bf16_t* Bb = Vt + (size_t)b * DD * SS + (size_t)nj * 128 * SS;
  float* Cb = Out + (size_t)b * SS * DD + (size_t)qi * 128 * DD + nj * 128;
  floatx4 acc[4][4];
  zero_acc(acc);
  mm_core(Ab, Bb, SS, SS, (qi + 1) * 2, sA, sB, acc);   // K = (qi+1)*128
  const int lane = threadIdx.x & 63;
  const int wm = (threadIdx.x >> 6) >> 1, wn = (threadIdx.x >> 6) & 1;
  const int m0 = wm * 64 + (lane & 15);          // q row
  const int n0 = wn * 64 + (lane >> 4) * 4;      // dv col
#pragma unroll
  for (int i2 = 0; i2 < 4; ++i2) {
    const float scale = sRl[m0 + i2 * 16];
    float* crow = Cb + (size_t)(m0 + i2 * 16) * DD + n0;
#pragma unroll
    for (int j = 0; j < 4; ++j) {
      floatx4 o = acc[i2][j];
      o[0] *= scale; o[1] *= scale; o[2] *= scale; o[3] *= scale;
      *(floatx4*)(crow + j * 16) = o;
    }
  }
}

// ---------------- launch ----------------

extern "C" void kernel_launch(void* const* d_in, const int* in_sizes, int n_in,
                              void* d_out, int out_size, void* d_ws, size_t ws_size,
                              hipStream_t stream) {
  const float* x  = (const float*)d_in[0];
  const float* Wq = (const float*)d_in[1];
  const float* Wk = (const float*)d_in[2];
  const float* Wv = (const float*)d_in[3];
  float* out = (float*)d_out;

  char* ws = (char*)d_ws;
  bf16_t* xb   = (bf16_t*)(ws);                      // 33,554,432  x bf16 [B*S, D]
  bf16_t* Wt   = (bf16_t*)(ws + 33554432ull);        //  6,291,456  Wq^T,Wk^T,Wv^T bf16 [N,K] each
  bf16_t* QKb  = (bf16_t*)(ws + 39845888ull);        // 67,108,864  [Q|K] bf16 [B*S, 2048]
  bf16_t* VtB  = (bf16_t*)(ws + 106954752ull);       // 33,554,432  V^T bf16 [B, D, S]
  bf16_t* Pb   = (bf16_t*)(ws + 140509184ull);       // 67,108,864  P' bf16 [B, S, S] (causal area only)
  float*  lpart= (float*)(ws + 207618048ull);        //  1,048,576  row-sum partials [B*S, 16]
  (void)in_sizes; (void)n_in; (void)out_size; (void)ws_size;

  // 1. convert x + convert/transpose weights (one dispatch)
  prep<<<16384 + 3072, 256, 0, stream>>>(x, Wq, Wk, Wv, xb, Wt);
  // 2. [Q|K] = x @ [Wq|Wk]  (M=16384, N=2048, K=1024), reg-pipelined core
  qkproj_gemm<<<dim3(64, 8), 512, 0, stream>>>(xb, Wt, QKb);
  // 3. V^T = Wv^T @ x^T, reg-pipelined core
  vproj_gemm<<<256, 512, 0, stream>>>(xb, Wt, VtB);
  // 4. P' = exp(QK^T/32) on causal tiles + row-sum partials, XCD==batch
  qk_p<<<1088, 256, 0, stream>>>(QKb, QKb + DD, Pb, lpart);
  // 5. out = (P' @ V) * (1/rowsum), causal K-truncation, XCD==batch, nj inner
  pv_gemm<<<1024, 256, 0, stream>>>(Pb, VtB, lpart, out);
}

// Round 6
// 440.395 us; speedup vs baseline: 1.1471x; 1.1471x over previous
//
#include <hip/hip_runtime.h>
#include <hip/hip_bf16.h>
#include <stdint.h>

// DecoderSelfAttention: B=8, S=2048, D=1024 (d_k=d_v=d_model)
// Pipeline (all bf16 MFMA, fp32 accumulate), 5 dispatches:
//   prep:    x->bf16, W->W^T bf16
//   qkproj:  [Q|K] = x@[Wq|Wk]      (256^2 BK=64 ring-2 core v6)
//   vproj:   V^T = Wv^T@x^T         (256^2 BK=64 ring-2 core v6)
//   qk_p:    P' = exp(QK^T/32) causal tiles + row-sum partials  (XCD==batch)
//   pv:      out = (P' @ V) * 1/rowsum                          (XCD==batch)
//
// mm256_core v6: 256x256 tile, BK=64, 512 thr (8 waves 2Mx4N, 128x64/wave),
// ring-2 K-tile buffers as FOUR DISTINCT 32KB __shared__ arrays (alias-clean,
// r3 lesson: fixed LDS objects stop the backend re-inserting vmcnt drains),
// loop unrolled x2 -> compile-time slots.
// r4/r5 lesson: 512-thr block = 2 waves/SIMD always -> HARD 256 reg/wave cap
// (arch+AGPR unified). Register frag double-buffering (v4/v5) cannot fit
// (acc 128 + 80 persistent + 48 transient) -> guaranteed scratch spill
// (WRITE_SIZE 66->163MB). v6 keeps r3's in-body reads (48 transient regs max).
// BK=64 halves the number of overhead phases per unit K (r3 vs m201 analysis:
// per-tile wall ~3100cyc is roughly fixed; doubling K per tile ~1.6x).
// Per body: stage(T+1) 8x global_load_lds; vmcnt(8) [tail 0]; BAR;
//   12 ds_read_b128 (kslot0); lgkmcnt(0); 32 MFMA;
//   12 ds_read_b128 (kslot1); lgkmcnt(0); 32 MFMA; BAR.
// Race proof: RAW: vmcnt(8) drains my tile-T loads before BAR -> all waves'
// tile T complete after BAR. WAR: stage(T+1) overwrites the slot last read at
// body T-1, whose reads retired (lgkmcnt 0) before body T-1's trailing BAR.
// LDS swizzle for 128B-stride rows: 8 16B-units/row; unit u of row r stored
// at u ^ ((r>>1)&7) (pre-swizzled global source; linear LDS dest for
// global_load_lds). Reader lane (fm,q) reads unit (kslot*4+q)^((fm>>1)&7):
// banks = 8 distinct 4-bank groups x 2-way aliasing -> conflict-free.

typedef __bf16 bf16_t;
typedef __bf16 bf16x4 __attribute__((ext_vector_type(4)));
typedef __bf16 bf16x8 __attribute__((ext_vector_type(8)));
typedef float  floatx4 __attribute__((ext_vector_type(4)));

#define NB 8
#define SS 2048
#define DD 1024
#define INV_SCALE 0.03125f   // 1/sqrt(1024)

__device__ __forceinline__ void async_ld16(const void* g, void* l) {
  __builtin_amdgcn_global_load_lds(
      (const __attribute__((address_space(1))) void*)g,
      (__attribute__((address_space(3))) void*)l, 16, 0, 0);
}

#define BARRIER() do { asm volatile("" ::: "memory"); \
  __builtin_amdgcn_s_barrier(); asm volatile("" ::: "memory"); } while (0)

// ---------------- 256x256 BK=64 ring-2 GEMM core v6 ----------------
// C = A * B^T, A[M,K] row-major, B[N,K] row-major, both bf16, BK=64.
// nt = number of 64-wide K steps; REQUIRES nt even, nt >= 2.
__device__ __forceinline__ void mm256_core(
    const bf16_t* __restrict__ Ab, const bf16_t* __restrict__ Bb,
    int lda, int ldb, int nt,
    bf16_t* sAX, bf16_t* sBX, bf16_t* sAY, bf16_t* sBY,
    floatx4 acc[8][4]) {
  const int t    = threadIdx.x;         // 0..511
  const int lane = t & 63;
  const int wid  = t >> 6;
  const int wm   = wid >> 2;            // 0..1
  const int wn   = wid & 3;             // 0..3
  const int fm   = lane & 15;
  const int q    = lane >> 4;           // 0..3 (k-group within 32-slot)
  const int xk   = (fm >> 1) & 7;       // 3-bit XOR swizzle key

  // staging: 4 rounds/op; round k: unit u=k*512+t; row=u>>3; phys slot p=u&7;
  // source unit = p ^ ((row>>1)&7) (pre-swizzled global address, linear LDS)
  size_t goA[4], goB[4]; int lo[4];
#pragma unroll
  for (int k = 0; k < 4; ++k) {
    const int u   = k * 512 + t;
    const int row = u >> 3;
    const int p   = u & 7;
    const int su  = p ^ ((row >> 1) & 7);
    goA[k] = (size_t)row * lda + su * 8;
    goB[k] = (size_t)row * ldb + su * 8;
    lo[k]  = u * 8;
  }

  auto stage = [&](bf16_t* la, bf16_t* lb, int tile) {
    const size_t ko = (size_t)tile * 64;
#pragma unroll
    for (int k = 0; k < 4; ++k) async_ld16(Ab + ko + goA[k], la + lo[k]);
#pragma unroll
    for (int k = 0; k < 4; ++k) async_ld16(Bb + ko + goB[k], lb + lo[k]);
  };

  const int paOff = (wm * 128 + fm) * 64;   // row stride 64 elems
  const int pbOff = (wn * 64 + fm) * 64;
  const int u0 = (0 * 4 + q) ^ xk;          // kslot0 physical unit
  const int u1 = (1 * 4 + q) ^ xk;          // kslot1 physical unit

  auto body = [&] __attribute__((always_inline)) (
      const bf16_t* CA, const bf16_t* CB, bf16_t* SA, bf16_t* SB, int T) {
    if (T + 1 < nt) {
      stage(SA, SB, T + 1);
      asm volatile("s_waitcnt vmcnt(8)" ::: "memory");  // tile T landed (mine)
    } else {
      asm volatile("s_waitcnt vmcnt(0)" ::: "memory");
    }
    BARRIER();                                           // ...everyone's

    const bf16_t* pa = CA + paOff;
    const bf16_t* pb = CB + pbOff;
    {   // k-slot 0
      bf16x8 af[8], bv[4];
#pragma unroll
      for (int i = 0; i < 8; ++i) af[i] = *(const bf16x8*)(pa + i * 1024 + u0 * 8);
#pragma unroll
      for (int j = 0; j < 4; ++j) bv[j] = *(const bf16x8*)(pb + j * 1024 + u0 * 8);
      asm volatile("s_waitcnt lgkmcnt(0)" ::: "memory");
      __builtin_amdgcn_sched_barrier(0);
      __builtin_amdgcn_s_setprio(1);
#pragma unroll
      for (int i = 0; i < 8; ++i)
#pragma unroll
        for (int j = 0; j < 4; ++j)
          acc[i][j] = __builtin_amdgcn_mfma_f32_16x16x32_bf16(bv[j], af[i], acc[i][j], 0, 0, 0);
      __builtin_amdgcn_s_setprio(0);
    }
    {   // k-slot 1
      bf16x8 af[8], bv[4];
#pragma unroll
      for (int i = 0; i < 8; ++i) af[i] = *(const bf16x8*)(pa + i * 1024 + u1 * 8);
#pragma unroll
      for (int j = 0; j < 4; ++j) bv[j] = *(const bf16x8*)(pb + j * 1024 + u1 * 8);
      asm volatile("s_waitcnt lgkmcnt(0)" ::: "memory");
      __builtin_amdgcn_sched_barrier(0);
      __builtin_amdgcn_s_setprio(1);
#pragma unroll
      for (int i = 0; i < 8; ++i)
#pragma unroll
        for (int j = 0; j < 4; ++j)
          acc[i][j] = __builtin_amdgcn_mfma_f32_16x16x32_bf16(bv[j], af[i], acc[i][j], 0, 0, 0);
      __builtin_amdgcn_s_setprio(0);
    }
    BARRIER();   // reads done before next body stages into this slot
  };

  stage(sAX, sBX, 0);
  for (int T = 0; T < nt; T += 2) {
    body(sAX, sBX, sAY, sBY, T);
    body(sAY, sBY, sAX, sBX, T + 1);
  }
}

__device__ __forceinline__ void zero_acc8(floatx4 acc[8][4]) {
#pragma unroll
  for (int i = 0; i < 8; ++i)
#pragma unroll
    for (int j = 0; j < 4; ++j)
      acc[i][j] = floatx4{0.f, 0.f, 0.f, 0.f};
}

__device__ __forceinline__ void store_c256_bf16(bf16_t* __restrict__ Cb, int ldc,
                                                floatx4 acc[8][4]) {
  const int lane = threadIdx.x & 63;
  const int wid  = threadIdx.x >> 6;
  const int wm = wid >> 2, wn = wid & 3;
  const int m0 = wm * 128 + (lane & 15);
  const int n0 = wn * 64 + (lane >> 4) * 4;
#pragma unroll
  for (int i = 0; i < 8; ++i)
#pragma unroll
    for (int j = 0; j < 4; ++j) {
      floatx4 a = acc[i][j];
      bf16x4 o = {(bf16_t)a[0], (bf16_t)a[1], (bf16_t)a[2], (bf16_t)a[3]};
      *(bf16x4*)(Cb + (size_t)(m0 + i * 16) * ldc + n0 + j * 16) = o;
    }
}

#define MM256_LDS_DECL                                                      \
  __shared__ __attribute__((aligned(16))) bf16_t sAX[16384], sAY[16384];    \
  __shared__ __attribute__((aligned(16))) bf16_t sBX[16384], sBY[16384];

// ---------------- 128x128 tile GEMM core (legacy, qk_p / pv) ----------------
__device__ __forceinline__ void mm_core(const bf16_t* __restrict__ Ab,
                                        const bf16_t* __restrict__ Bb,
                                        int lda, int ldb, int kTiles,
                                        bf16_t* sA, bf16_t* sB,
                                        floatx4 acc[4][4]) {
  const int t    = threadIdx.x;
  const int lane = t & 63;
  const int wm   = (t >> 6) >> 1;
  const int wn   = (t >> 6) & 1;
  const int fm   = lane & 15;
  const int q    = lane >> 4;       // 0..3
  const int xo   = fm & 7;          // per-lane XOR swizzle key

  const bf16_t* ga[4]; const bf16_t* gb[4];
  bf16_t* la[4]; bf16_t* lb[4];
#pragma unroll
  for (int k = 0; k < 4; ++k) {
    const int u   = k * 256 + t;
    const int row = u >> 3;
    const int cc  = (u & 7) ^ (row & 7);
    ga[k] = Ab + (size_t)row * lda + cc * 8;
    gb[k] = Bb + (size_t)row * ldb + cc * 8;
    la[k] = sA + u * 8;
    lb[k] = sB + u * 8;
  }

  const bf16_t* pa = sA + (wm * 64 + fm) * 64;
  const bf16_t* pb = sB + (wn * 64 + fm) * 64;

  for (int kt = 0; kt < kTiles; ++kt) {
    const int ko = kt * 64;
#pragma unroll
    for (int k = 0; k < 4; ++k) async_ld16(ga[k] + ko, la[k]);
#pragma unroll
    for (int k = 0; k < 4; ++k) async_ld16(gb[k] + ko, lb[k]);
    __syncthreads();
#pragma unroll
    for (int h = 0; h < 2; ++h) {
      const int co = ((h * 4 + q) ^ xo) * 8;
      bf16x8 af[4], bfr[4];
#pragma unroll
      for (int i = 0; i < 4; ++i) af[i]  = *(const bf16x8*)(pa + i * 1024 + co);
#pragma unroll
      for (int j = 0; j < 4; ++j) bfr[j] = *(const bf16x8*)(pb + j * 1024 + co);
#pragma unroll
      for (int i = 0; i < 4; ++i)
#pragma unroll
        for (int j = 0; j < 4; ++j)
          acc[i][j] = __builtin_amdgcn_mfma_f32_16x16x32_bf16(bfr[j], af[i], acc[i][j], 0, 0, 0);
    }
    __syncthreads();
  }
}

__device__ __forceinline__ void zero_acc(floatx4 acc[4][4]) {
#pragma unroll
  for (int i = 0; i < 4; ++i)
#pragma unroll
    for (int j = 0; j < 4; ++j)
      acc[i][j] = floatx4{0.f, 0.f, 0.f, 0.f};
}

// ---------------- fused converters: x->bf16 and W->W^T bf16 ----------------

__global__ __launch_bounds__(256) void prep(const float* __restrict__ x,
                                            const float* __restrict__ Wq,
                                            const float* __restrict__ Wk,
                                            const float* __restrict__ Wv,
                                            bf16_t* __restrict__ xb,
                                            bf16_t* __restrict__ Wt) {
  __shared__ float tile[32][33];
  const int bid = blockIdx.x;
  const int t = threadIdx.x;
  if (bid < 16384) {
    size_t i = (size_t)bid * 256 + t;
    float4 v = ((const float4*)x)[i];
    bf16x4 o = {(bf16_t)v.x, (bf16_t)v.y, (bf16_t)v.z, (bf16_t)v.w};
    ((bf16x4*)xb)[i] = o;
  } else {
    const int wb = bid - 16384;
    const int z = wb >> 10;                 // 0,1,2 -> Wq,Wk,Wv
    const int rem = wb & 1023;
    const float* W = (z == 0) ? Wq : (z == 1 ? Wk : Wv);
    bf16_t* O = Wt + (size_t)z * DD * DD;
    const int ty = t >> 3;
    const int tx = t & 7;
    const int k0 = (rem >> 5) * 32, n0 = (rem & 31) * 32;
    float4 v = *(const float4*)(W + (size_t)(k0 + ty) * DD + n0 + tx * 4);
    tile[ty][tx * 4 + 0] = v.x;
    tile[ty][tx * 4 + 1] = v.y;
    tile[ty][tx * 4 + 2] = v.z;
    tile[ty][tx * 4 + 3] = v.w;
    __syncthreads();
    bf16x4 o = {(bf16_t)tile[tx * 4 + 0][ty], (bf16_t)tile[tx * 4 + 1][ty],
                (bf16_t)tile[tx * 4 + 2][ty], (bf16_t)tile[tx * 4 + 3][ty]};
    *(bf16x4*)(O + (size_t)(n0 + ty) * DD + k0 + tx * 4) = o;
  }
}

// ---------------- QK projection: [Q|K] = x @ [Wq|Wk] ----------------

__global__ __launch_bounds__(512, 1) void qkproj_gemm(
    const bf16_t* __restrict__ xb, const bf16_t* __restrict__ Wt,
    bf16_t* __restrict__ QKb) {
  MM256_LDS_DECL
  const int mt = blockIdx.x, nt = blockIdx.y;
  const bf16_t* Ab = xb + (size_t)mt * 256 * DD;
  const bf16_t* Bb = Wt + (size_t)nt * 256 * DD;
  bf16_t* Cb = QKb + (size_t)mt * 256 * (2 * DD) + nt * 256;
  floatx4 acc[8][4];
  zero_acc8(acc);
  mm256_core(Ab, Bb, DD, DD, DD / 64, sAX, sBX, sAY, sBY, acc);
  store_c256_bf16(Cb, 2 * DD, acc);
}

// ---------------- V projection: V^T[b] = Wv^T @ x[b]^T ----------------
// 1D grid 256: n = bid&7 (XCD), m = (bid>>3)&3, b = bid>>5. 1 block/CU.

__global__ __launch_bounds__(512, 1) void vproj_gemm(
    const bf16_t* __restrict__ xb, const bf16_t* __restrict__ Wt,
    bf16_t* __restrict__ VtB) {
  MM256_LDS_DECL
  const int bid = blockIdx.x;
  const int n = bid & 7;            // seq tile (256 rows)
  const int m = (bid >> 3) & 3;     // dv tile (256 rows)
  const int b = bid >> 5;           // batch
  const bf16_t* Ab = Wt + (size_t)2 * DD * DD + (size_t)m * 256 * DD;
  const bf16_t* Bb = xb + (size_t)b * SS * DD + (size_t)n * 256 * DD;
  bf16_t* Cb = VtB + (size_t)b * DD * SS + (size_t)m * 256 * SS + n * 256;
  floatx4 acc[8][4];
  zero_acc8(acc);
  mm256_core(Ab, Bb, DD, DD, DD / 64, sAX, sBX, sAY, sBY, acc);
  store_c256_bf16(Cb, SS, acc);
}

// ---------------- QK^T -> P' = exp(s) bf16 (causal tiles only) + row-sum partials ----------------
// 1D grid 1088: b = bid&7 (XCD==batch), tt = 135-(bid>>3) (qi descending).

__global__ __launch_bounds__(256) void qk_p(
    const bf16_t* __restrict__ Q, const bf16_t* __restrict__ K,
    bf16_t* __restrict__ P, float* __restrict__ lpart) {
  const int b  = blockIdx.x & 7;
  const int tt = 135 - (blockIdx.x >> 3);
  int qi = (int)((sqrtf(8.0f * tt + 1.0f) - 1.0f) * 0.5f);
  while ((qi + 1) * (qi + 2) / 2 <= tt) ++qi;
  while (qi * (qi + 1) / 2 > tt) --qi;
  const int ki = tt - qi * (qi + 1) / 2;

  __shared__ __attribute__((aligned(16))) bf16_t sA[128 * 64];
  __shared__ __attribute__((aligned(16))) bf16_t sB[128 * 64];
  __shared__ float reds[2][128];
  const bf16_t* Ab = Q + ((size_t)b * SS + qi * 128) * (size_t)(2 * DD);
  const bf16_t* Bb = K + ((size_t)b * SS + ki * 128) * (size_t)(2 * DD);
  floatx4 acc[4][4];
  zero_acc(acc);
  mm_core(Ab, Bb, 2 * DD, 2 * DD, DD / 64, sA, sB, acc);

  const int lane = threadIdx.x & 63;
  const int wm = (threadIdx.x >> 6) >> 1, wn = (threadIdx.x >> 6) & 1;
  const bool diag = (ki == qi);
  bf16_t* Pb = P + (size_t)b * SS * SS;
  const int qloc0 = wm * 64 + (lane & 15);        // + i*16
  const int kvb0  = wn * 64 + (lane >> 4) * 4;    // + j*16, + reg

#pragma unroll
  for (int i = 0; i < 4; ++i) {
    const int qrow = qloc0 + i * 16;
    float partial = 0.f;
#pragma unroll
    for (int j = 0; j < 4; ++j) {
      const int kvb = kvb0 + j * 16;
      floatx4 p;
#pragma unroll
      for (int r = 0; r < 4; ++r) {
        const float s = acc[i][j][r] * INV_SCALE;
        p[r] = (diag && (kvb + r) > qrow) ? 0.f : __expf(s);
        partial += p[r];
      }
      bf16x4 o = {(bf16_t)p[0], (bf16_t)p[1], (bf16_t)p[2], (bf16_t)p[3]};
      *(bf16x4*)(Pb + (size_t)(qi * 128 + qrow) * SS + ki * 128 + kvb) = o;
    }
    partial += __shfl_xor(partial, 16);
    partial += __shfl_xor(partial, 32);
    if ((lane >> 4) == 0) reds[wn][qrow] = partial;
  }
  __syncthreads();
  const int t = threadIdx.x;
  if (t < 128) {
    size_t row = (size_t)b * SS + qi * 128 + t;
    lpart[row * 16 + ki] = reds[0][t] + reds[1][t];
  }
}

// ---------------- PV GEMM (causal-truncated K-loop), rowsum+scale folded, fp32 out ----------------
// 1D grid 1024: b = bid&7 (XCD==batch), nj = (bid>>3)&7, qi = 15-(bid>>6) desc.

__global__ __launch_bounds__(256) void pv_gemm(
    const bf16_t* __restrict__ P, const bf16_t* __restrict__ Vt,
    const float* __restrict__ lpart, float* __restrict__ Out) {
  const int bid = blockIdx.x;
  const int b  = bid & 7;
  const int nj = (bid >> 3) & 7;
  const int qi = 15 - (bid >> 6);

  __shared__ __attribute__((aligned(16))) bf16_t sA[128 * 64];
  __shared__ __attribute__((aligned(16))) bf16_t sB[128 * 64];
  __shared__ float sRl[128];
  const int t = threadIdx.x;
  if (t < 128) {
    const float* lp = lpart + ((size_t)b * SS + qi * 128 + t) * 16;
    float L = 0.f;
    for (int ci = 0; ci <= qi; ++ci) L += lp[ci];
    sRl[t] = 1.0f / L;
  }
  const bf16_t* Ab = P + (size_t)b * SS * SS + (size_t)qi * 128 * SS;
  const bf16_t* Bb = Vt + (size_t)b * DD * SS + (size_t)nj * 128 * SS;
  float* Cb = Out + (size_t)b * SS * DD + (size_t)qi * 128 * DD + nj * 128;
  floatx4 acc[4][4];
  zero_acc(acc);
  mm_core(Ab, Bb, SS, SS, (qi + 1) * 2, sA, sB, acc);   // K = (qi+1)*128
  const int lane = threadIdx.x & 63;
  const int wm = (threadIdx.x >> 6) >> 1, wn = (threadIdx.x >> 6) & 1;
  const int m0 = wm * 64 + (lane & 15);          // q row
  const int n0 = wn * 64 + (lane >> 4) * 4;      // dv col
#pragma unroll
  for (int i2 = 0; i2 < 4; ++i2) {
    const float scale = sRl[m0 + i2 * 16];
    float* crow = Cb + (size_t)(m0 + i2 * 16) * DD + n0;
#pragma unroll
    for (int j = 0; j < 4; ++j) {
      floatx4 o = acc[i2][j];
      o[0] *= scale; o[1] *= scale; o[2] *= scale; o[3] *= scale;
      *(floatx4*)(crow + j * 16) = o;
    }
  }
}

// ---------------- launch ----------------

extern "C" void kernel_launch(void* const* d_in, const int* in_sizes, int n_in,
                              void* d_out, int out_size, void* d_ws, size_t ws_size,
                              hipStream_t stream) {
  const float* x  = (const float*)d_in[0];
  const float* Wq = (const float*)d_in[1];
  const float* Wk = (const float*)d_in[2];
  const float* Wv = (const float*)d_in[3];
  float* out = (float*)d_out;

  char* ws = (char*)d_ws;
  bf16_t* xb   = (bf16_t*)(ws);                      // 33,554,432  x bf16 [B*S, D]
  bf16_t* Wt   = (bf16_t*)(ws + 33554432ull);        //  6,291,456  Wq^T,Wk^T,Wv^T bf16 [N,K] each
  bf16_t* QKb  = (bf16_t*)(ws + 39845888ull);        // 67,108,864  [Q|K] bf16 [B*S, 2048]
  bf16_t* VtB  = (bf16_t*)(ws + 106954752ull);       // 33,554,432  V^T bf16 [B, D, S]
  bf16_t* Pb   = (bf16_t*)(ws + 140509184ull);       // 67,108,864  P' bf16 [B, S, S] (causal area only)
  float*  lpart= (float*)(ws + 207618048ull);        //  1,048,576  row-sum partials [B*S, 16]
  (void)in_sizes; (void)n_in; (void)out_size; (void)ws_size;

  // 1. convert x + convert/transpose weights (one dispatch)
  prep<<<16384 + 3072, 256, 0, stream>>>(x, Wq, Wk, Wv, xb, Wt);
  // 2. [Q|K] = x @ [Wq|Wk]  (M=16384, N=2048, K=1024), BK=64 ring-2 core
  qkproj_gemm<<<dim3(64, 8), 512, 0, stream>>>(xb, Wt, QKb);
  // 3. V^T = Wv^T @ x^T, BK=64 ring-2 core
  vproj_gemm<<<256, 512, 0, stream>>>(xb, Wt, VtB);
  // 4. P' = exp(QK^T/32) on causal tiles + row-sum partials, XCD==batch
  qk_p<<<1088, 256, 0, stream>>>(QKb, QKb + DD, Pb, lpart);
  // 5. out = (P' @ V) * (1/rowsum), causal K-truncation, XCD==batch, nj inner
  pv_gemm<<<1024, 256, 0, stream>>>(Pb, VtB, lpart, out);
}

// Round 7
// 351.145 us; speedup vs baseline: 1.4387x; 1.2542x over previous
//
#include <hip/hip_runtime.h>
#include <hip/hip_bf16.h>
#include <stdint.h>

// DecoderSelfAttention: B=8, S=2048, D=1024 (d_k=d_v=d_model)
// Pipeline (all bf16 MFMA, fp32 accumulate), 5 dispatches:
//   prep:    x->bf16, W->W^T bf16
//   qkproj:  [Q|K] = x@[Wq|Wk]      (256^2 alias-clean ring-4 core, r3 exact)
//   vproj:   V^T = Wv^T@x^T         (256^2 alias-clean ring-4 core, r3 exact)
//   qk_p:    P' = exp(QK^T/32) causal tiles + row-sum partials  (XCD==batch)
//            -> NOW on mm_core2 (ring-2 alias-clean, counted vmcnt)
//   pv:      out = (P' @ V) * 1/rowsum                          (XCD==batch)
//            -> NOW on mm_core2
//
// r6 post-mortem: BK=64 body carries MORE overhead than 2x BK=32 bodies
// (10.2k cyc wall vs 2k MFMA; spill traffic returned). r3 is the only
// confirmed-good GEMM core config: revert projections to it verbatim.
// This round's single variable: port the r3 pattern (ring-2 distinct LDS
// objects + stage-ahead + counted vmcnt(8), 1 barrier-pair/tile) into the
// 128^2 core used by qk_p/pv, which until now did stage->full-drain->compute.
// Race proof (mm_core2): RAW: vmcnt(8) drains my tile-T loads before BAR ->
// after BAR all waves' tile T is in LDS. WAR: stage(T+1) writes the buffer
// whose last reads retired (lgkmcnt 0) before body T-1's trailing BAR.
// nt must be even: qk_p nt=16; pv nt=(qi+1)*2 in {2..32}. OK.

typedef __bf16 bf16_t;
typedef __bf16 bf16x4 __attribute__((ext_vector_type(4)));
typedef __bf16 bf16x8 __attribute__((ext_vector_type(8)));
typedef float  floatx4 __attribute__((ext_vector_type(4)));

#define NB 8
#define SS 2048
#define DD 1024
#define INV_SCALE 0.03125f   // 1/sqrt(1024)

__device__ __forceinline__ void async_ld16(const void* g, void* l) {
  __builtin_amdgcn_global_load_lds(
      (const __attribute__((address_space(1))) void*)g,
      (__attribute__((address_space(3))) void*)l, 16, 0, 0);
}

#define BARRIER() do { asm volatile("" ::: "memory"); \
  __builtin_amdgcn_s_barrier(); asm volatile("" ::: "memory"); } while (0)

// ---------------- 256x256 alias-clean ring-4 GEMM core (r3 exact) ----------------
// C = A * B^T, A[M,K] row-major, B[N,K] row-major, both bf16, BK=32.
// nt = number of 32-wide K steps; REQUIRES nt % 4 == 0, nt >= 4.
__device__ __forceinline__ void mm256_core(
    const bf16_t* __restrict__ Ab, const bf16_t* __restrict__ Bb,
    int lda, int ldb, int nt,
    bf16_t* sA0, bf16_t* sA1, bf16_t* sA2, bf16_t* sA3,
    bf16_t* sB0, bf16_t* sB1, bf16_t* sB2, bf16_t* sB3,
    floatx4 acc[8][4]) {
  const int t    = threadIdx.x;         // 0..511
  const int lane = t & 63;
  const int wid  = t >> 6;
  const int wm   = wid >> 2;            // 0..1
  const int wn   = wid & 3;             // 0..3
  const int fm   = lane & 15;
  const int q    = lane >> 4;           // 0..3 (k-group)
  const int co   = (q ^ ((fm >> 1) & 3)) * 8;   // swizzled k-group offset

  // staging: 2 units/thread/operand; unit u: row=u>>2, src group=(u&3)^((row>>1)&3)
  size_t goA[2], goB[2]; int lo[2];
#pragma unroll
  for (int k = 0; k < 2; ++k) {
    const int u   = k * 512 + t;
    const int row = u >> 2;
    const int cg  = (u & 3) ^ ((row >> 1) & 3);
    goA[k] = (size_t)row * lda + cg * 8;
    goB[k] = (size_t)row * ldb + cg * 8;
    lo[k]  = u * 8;
  }

  auto stage = [&](bf16_t* la, bf16_t* lb, int tile) {
    const size_t ko = (size_t)tile * 32;
    async_ld16(Ab + ko + goA[0], la + lo[0]);
    async_ld16(Ab + ko + goA[1], la + lo[1]);
    async_ld16(Bb + ko + goB[0], lb + lo[0]);
    async_ld16(Bb + ko + goB[1], lb + lo[1]);
  };

  const int paOff = (wm * 128 + fm) * 32;
  const int pbOff = (wn * 64 + fm) * 32;

  // per-tile body; AP/BP = compute buffers (tile T), AN/BN = stage buffers
  // (tile T+3). All four resolve to fixed __shared__ objects after inlining.
  auto body = [&] __attribute__((always_inline)) (
      const bf16_t* AP, const bf16_t* BP, bf16_t* AN, bf16_t* BN, int T) {
    if (T + 3 < nt) {
      stage(AN, BN, T + 3);
      asm volatile("s_waitcnt vmcnt(12)" ::: "memory");  // tile T landed
    } else if (T + 2 < nt) {
      asm volatile("s_waitcnt vmcnt(8)" ::: "memory");
    } else if (T + 1 < nt) {
      asm volatile("s_waitcnt vmcnt(4)" ::: "memory");
    } else {
      asm volatile("s_waitcnt vmcnt(0)" ::: "memory");
    }
    __builtin_amdgcn_s_barrier();        // all waves' tile-T loads visible
    asm volatile("" ::: "memory");

    const bf16_t* pa = AP + paOff;
    const bf16_t* pb = BP + pbOff;
    bf16x8 a0[4], a1[4], bv[4];
#pragma unroll
    for (int i = 0; i < 4; ++i) a0[i] = *(const bf16x8*)(pa + i * 512 + co);
#pragma unroll
    for (int j = 0; j < 4; ++j) bv[j] = *(const bf16x8*)(pb + j * 512 + co);
    __builtin_amdgcn_sched_barrier(0);   // pin group1 (8 reads) before group2
#pragma unroll
    for (int i = 0; i < 4; ++i) a1[i] = *(const bf16x8*)(pa + (4 + i) * 512 + co);

    asm volatile("s_waitcnt lgkmcnt(4)" ::: "memory");   // a0/bv landed
    __builtin_amdgcn_sched_barrier(0);
    __builtin_amdgcn_s_setprio(1);
#pragma unroll
    for (int i = 0; i < 4; ++i)
#pragma unroll
      for (int j = 0; j < 4; ++j)
        acc[i][j] = __builtin_amdgcn_mfma_f32_16x16x32_bf16(bv[j], a0[i], acc[i][j], 0, 0, 0);
    __builtin_amdgcn_s_setprio(0);

    asm volatile("s_waitcnt lgkmcnt(0)" ::: "memory");   // a1 landed
    __builtin_amdgcn_sched_barrier(0);
    __builtin_amdgcn_s_setprio(1);
#pragma unroll
    for (int i = 0; i < 4; ++i)
#pragma unroll
      for (int j = 0; j < 4; ++j)
        acc[4 + i][j] = __builtin_amdgcn_mfma_f32_16x16x32_bf16(bv[j], a1[i], acc[4 + i][j], 0, 0, 0);
    __builtin_amdgcn_s_setprio(0);
    asm volatile("" ::: "memory");
    __builtin_amdgcn_s_barrier();        // reads done before slot reuse
  };

  // prologue: fill 3 ring slots
  stage(sA0, sB0, 0);
  stage(sA1, sB1, 1);
  stage(sA2, sB2, 2);

  for (int tb = 0; tb < nt; tb += 4) {
    body(sA0, sB0, sA3, sB3, tb + 0);
    body(sA1, sB1, sA0, sB0, tb + 1);
    body(sA2, sB2, sA1, sB1, tb + 2);
    body(sA3, sB3, sA2, sB2, tb + 3);
  }
}

__device__ __forceinline__ void zero_acc8(floatx4 acc[8][4]) {
#pragma unroll
  for (int i = 0; i < 8; ++i)
#pragma unroll
    for (int j = 0; j < 4; ++j)
      acc[i][j] = floatx4{0.f, 0.f, 0.f, 0.f};
}

__device__ __forceinline__ void store_c256_bf16(bf16_t* __restrict__ Cb, int ldc,
                                                floatx4 acc[8][4]) {
  const int lane = threadIdx.x & 63;
  const int wid  = threadIdx.x >> 6;
  const int wm = wid >> 2, wn = wid & 3;
  const int m0 = wm * 128 + (lane & 15);
  const int n0 = wn * 64 + (lane >> 4) * 4;
#pragma unroll
  for (int i = 0; i < 8; ++i)
#pragma unroll
    for (int j = 0; j < 4; ++j) {
      floatx4 a = acc[i][j];
      bf16x4 o = {(bf16_t)a[0], (bf16_t)a[1], (bf16_t)a[2], (bf16_t)a[3]};
      *(bf16x4*)(Cb + (size_t)(m0 + i * 16) * ldc + n0 + j * 16) = o;
    }
}

#define MM256_LDS_DECL                                                      \
  __shared__ __attribute__((aligned(16))) bf16_t sA0[8192], sA1[8192],      \
      sA2[8192], sA3[8192];                                                 \
  __shared__ __attribute__((aligned(16))) bf16_t sB0[8192], sB1[8192],      \
      sB2[8192], sB3[8192];

// ---------------- 128x128 ring-2 GEMM core v2 (qk_p / pv) ----------------
// C = A * B^T, A[M,K] row-major, B[N,K] row-major, bf16, BK=64, 256 thr
// (4 waves 2x2), acc 4x4. nt counts 64-wide K steps; REQUIRES nt even >= 2.
// Ring-2 as FOUR DISTINCT __shared__ arrays (alias-clean); stage(T+1) before
// compute(T); counted vmcnt(8) (tail 0); one barrier pair per tile.
__device__ __forceinline__ void mm_core2(
    const bf16_t* __restrict__ Ab, const bf16_t* __restrict__ Bb,
    int lda, int ldb, int nt,
    bf16_t* sA0, bf16_t* sB0, bf16_t* sA1, bf16_t* sB1,
    floatx4 acc[4][4]) {
  const int t    = threadIdx.x;
  const int lane = t & 63;
  const int wm   = (t >> 6) >> 1;
  const int wn   = (t >> 6) & 1;
  const int fm   = lane & 15;
  const int q    = lane >> 4;       // 0..3
  const int xo   = fm & 7;          // per-lane XOR swizzle key

  // staging: 4 rounds/op; unit u = k*256+t; row=u>>3; cc=(u&7)^(row&7)
  size_t goA[4], goB[4]; int lo[4];
#pragma unroll
  for (int k = 0; k < 4; ++k) {
    const int u   = k * 256 + t;
    const int row = u >> 3;
    const int cc  = (u & 7) ^ (row & 7);
    goA[k] = (size_t)row * lda + cc * 8;
    goB[k] = (size_t)row * ldb + cc * 8;
    lo[k]  = u * 8;
  }

  auto stage = [&](bf16_t* la, bf16_t* lb, int tile) {
    const size_t ko = (size_t)tile * 64;
#pragma unroll
    for (int k = 0; k < 4; ++k) async_ld16(Ab + ko + goA[k], la + lo[k]);
#pragma unroll
    for (int k = 0; k < 4; ++k) async_ld16(Bb + ko + goB[k], lb + lo[k]);
  };

  const int paOff = (wm * 64 + fm) * 64;
  const int pbOff = (wn * 64 + fm) * 64;

  auto body = [&] __attribute__((always_inline)) (
      const bf16_t* CA, const bf16_t* CB, bf16_t* SA, bf16_t* SB, int T) {
    if (T + 1 < nt) {
      stage(SA, SB, T + 1);
      asm volatile("s_waitcnt vmcnt(8)" ::: "memory");  // tile T landed (mine)
    } else {
      asm volatile("s_waitcnt vmcnt(0)" ::: "memory");
    }
    BARRIER();                                           // ...everyone's

    const bf16_t* pa = CA + paOff;
    const bf16_t* pb = CB + pbOff;
#pragma unroll
    for (int h = 0; h < 2; ++h) {
      const int co = ((h * 4 + q) ^ xo) * 8;
      bf16x8 af[4], bfr[4];
#pragma unroll
      for (int i = 0; i < 4; ++i) af[i]  = *(const bf16x8*)(pa + i * 1024 + co);
#pragma unroll
      for (int j = 0; j < 4; ++j) bfr[j] = *(const bf16x8*)(pb + j * 1024 + co);
      asm volatile("s_waitcnt lgkmcnt(0)" ::: "memory");
      __builtin_amdgcn_sched_barrier(0);
      __builtin_amdgcn_s_setprio(1);
#pragma unroll
      for (int i = 0; i < 4; ++i)
#pragma unroll
        for (int j = 0; j < 4; ++j)
          acc[i][j] = __builtin_amdgcn_mfma_f32_16x16x32_bf16(bfr[j], af[i], acc[i][j], 0, 0, 0);
      __builtin_amdgcn_s_setprio(0);
    }
    BARRIER();   // reads done before next body stages into this buffer pair
  };

  stage(sA0, sB0, 0);
  for (int T = 0; T < nt; T += 2) {
    body(sA0, sB0, sA1, sB1, T);
    body(sA1, sB1, sA0, sB0, T + 1);
  }
}

__device__ __forceinline__ void zero_acc(floatx4 acc[4][4]) {
#pragma unroll
  for (int i = 0; i < 4; ++i)
#pragma unroll
    for (int j = 0; j < 4; ++j)
      acc[i][j] = floatx4{0.f, 0.f, 0.f, 0.f};
}

#define MM128_LDS_DECL                                                      \
  __shared__ __attribute__((aligned(16))) bf16_t sA0[128 * 64], sA1[128 * 64]; \
  __shared__ __attribute__((aligned(16))) bf16_t sB0[128 * 64], sB1[128 * 64];

// ---------------- fused converters: x->bf16 and W->W^T bf16 ----------------

__global__ __launch_bounds__(256) void prep(const float* __restrict__ x,
                                            const float* __restrict__ Wq,
                                            const float* __restrict__ Wk,
                                            const float* __restrict__ Wv,
                                            bf16_t* __restrict__ xb,
                                            bf16_t* __restrict__ Wt) {
  __shared__ float tile[32][33];
  const int bid = blockIdx.x;
  const int t = threadIdx.x;
  if (bid < 16384) {
    size_t i = (size_t)bid * 256 + t;
    float4 v = ((const float4*)x)[i];
    bf16x4 o = {(bf16_t)v.x, (bf16_t)v.y, (bf16_t)v.z, (bf16_t)v.w};
    ((bf16x4*)xb)[i] = o;
  } else {
    const int wb = bid - 16384;
    const int z = wb >> 10;                 // 0,1,2 -> Wq,Wk,Wv
    const int rem = wb & 1023;
    const float* W = (z == 0) ? Wq : (z == 1 ? Wk : Wv);
    bf16_t* O = Wt + (size_t)z * DD * DD;
    const int ty = t >> 3;
    const int tx = t & 7;
    const int k0 = (rem >> 5) * 32, n0 = (rem & 31) * 32;
    float4 v = *(const float4*)(W + (size_t)(k0 + ty) * DD + n0 + tx * 4);
    tile[ty][tx * 4 + 0] = v.x;
    tile[ty][tx * 4 + 1] = v.y;
    tile[ty][tx * 4 + 2] = v.z;
    tile[ty][tx * 4 + 3] = v.w;
    __syncthreads();
    bf16x4 o = {(bf16_t)tile[tx * 4 + 0][ty], (bf16_t)tile[tx * 4 + 1][ty],
                (bf16_t)tile[tx * 4 + 2][ty], (bf16_t)tile[tx * 4 + 3][ty]};
    *(bf16x4*)(O + (size_t)(n0 + ty) * DD + k0 + tx * 4) = o;
  }
}

// ---------------- QK projection: [Q|K] = x @ [Wq|Wk] ----------------

__global__ __launch_bounds__(512, 2) void qkproj_gemm(
    const bf16_t* __restrict__ xb, const bf16_t* __restrict__ Wt,
    bf16_t* __restrict__ QKb) {
  MM256_LDS_DECL
  const int mt = blockIdx.x, nt = blockIdx.y;
  const bf16_t* Ab = xb + (size_t)mt * 256 * DD;
  const bf16_t* Bb = Wt + (size_t)nt * 256 * DD;
  bf16_t* Cb = QKb + (size_t)mt * 256 * (2 * DD) + nt * 256;
  floatx4 acc[8][4];
  zero_acc8(acc);
  mm256_core(Ab, Bb, DD, DD, DD / 32,
             sA0, sA1, sA2, sA3, sB0, sB1, sB2, sB3, acc);
  store_c256_bf16(Cb, 2 * DD, acc);
}

// ---------------- V projection: V^T[b] = Wv^T @ x[b]^T ----------------
// 1D grid 256: n = bid&7 (XCD), m = (bid>>3)&3, b = bid>>5. 1 block/CU.

__global__ __launch_bounds__(512, 2) void vproj_gemm(
    const bf16_t* __restrict__ xb, const bf16_t* __restrict__ Wt,
    bf16_t* __restrict__ VtB) {
  MM256_LDS_DECL
  const int bid = blockIdx.x;
  const int n = bid & 7;            // seq tile (256 rows)
  const int m = (bid >> 3) & 3;     // dv tile (256 rows)
  const int b = bid >> 5;           // batch
  const bf16_t* Ab = Wt + (size_t)2 * DD * DD + (size_t)m * 256 * DD;
  const bf16_t* Bb = xb + (size_t)b * SS * DD + (size_t)n * 256 * DD;
  bf16_t* Cb = VtB + (size_t)b * DD * SS + (size_t)m * 256 * SS + n * 256;
  floatx4 acc[8][4];
  zero_acc8(acc);
  mm256_core(Ab, Bb, DD, DD, DD / 32,
             sA0, sA1, sA2, sA3, sB0, sB1, sB2, sB3, acc);
  store_c256_bf16(Cb, SS, acc);
}

// ---------------- QK^T -> P' = exp(s) bf16 (causal tiles only) + row-sum partials ----------------
// 1D grid 1088: b = bid&7 (XCD==batch), tt = 135-(bid>>3) (qi descending).

__global__ __launch_bounds__(256) void qk_p(
    const bf16_t* __restrict__ Q, const bf16_t* __restrict__ K,
    bf16_t* __restrict__ P, float* __restrict__ lpart) {
  const int b  = blockIdx.x & 7;
  const int tt = 135 - (blockIdx.x >> 3);
  int qi = (int)((sqrtf(8.0f * tt + 1.0f) - 1.0f) * 0.5f);
  while ((qi + 1) * (qi + 2) / 2 <= tt) ++qi;
  while (qi * (qi + 1) / 2 > tt) --qi;
  const int ki = tt - qi * (qi + 1) / 2;

  MM128_LDS_DECL
  __shared__ float reds[2][128];
  const bf16_t* Ab = Q + ((size_t)b * SS + qi * 128) * (size_t)(2 * DD);
  const bf16_t* Bb = K + ((size_t)b * SS + ki * 128) * (size_t)(2 * DD);
  floatx4 acc[4][4];
  zero_acc(acc);
  mm_core2(Ab, Bb, 2 * DD, 2 * DD, DD / 64, sA0, sB0, sA1, sB1, acc);

  const int lane = threadIdx.x & 63;
  const int wm = (threadIdx.x >> 6) >> 1, wn = (threadIdx.x >> 6) & 1;
  const bool diag = (ki == qi);
  bf16_t* Pb = P + (size_t)b * SS * SS;
  const int qloc0 = wm * 64 + (lane & 15);        // + i*16
  const int kvb0  = wn * 64 + (lane >> 4) * 4;    // + j*16, + reg

#pragma unroll
  for (int i = 0; i < 4; ++i) {
    const int qrow = qloc0 + i * 16;
    float partial = 0.f;
#pragma unroll
    for (int j = 0; j < 4; ++j) {
      const int kvb = kvb0 + j * 16;
      floatx4 p;
#pragma unroll
      for (int r = 0; r < 4; ++r) {
        const float s = acc[i][j][r] * INV_SCALE;
        p[r] = (diag && (kvb + r) > qrow) ? 0.f : __expf(s);
        partial += p[r];
      }
      bf16x4 o = {(bf16_t)p[0], (bf16_t)p[1], (bf16_t)p[2], (bf16_t)p[3]};
      *(bf16x4*)(Pb + (size_t)(qi * 128 + qrow) * SS + ki * 128 + kvb) = o;
    }
    partial += __shfl_xor(partial, 16);
    partial += __shfl_xor(partial, 32);
    if ((lane >> 4) == 0) reds[wn][qrow] = partial;
  }
  __syncthreads();
  const int t = threadIdx.x;
  if (t < 128) {
    size_t row = (size_t)b * SS + qi * 128 + t;
    lpart[row * 16 + ki] = reds[0][t] + reds[1][t];
  }
}

// ---------------- PV GEMM (causal-truncated K-loop), rowsum+scale folded, fp32 out ----------------
// 1D grid 1024: b = bid&7 (XCD==batch), nj = (bid>>3)&7, qi = 15-(bid>>6) desc.

__global__ __launch_bounds__(256) void pv_gemm(
    const bf16_t* __restrict__ P, const bf16_t* __restrict__ Vt,
    const float* __restrict__ lpart, float* __restrict__ Out) {
  const int bid = blockIdx.x;
  const int b  = bid & 7;
  const int nj = (bid >> 3) & 7;
  const int qi = 15 - (bid >> 6);

  MM128_LDS_DECL
  __shared__ float sRl[128];
  const int t = threadIdx.x;
  if (t < 128) {
    const float* lp = lpart + ((size_t)b * SS + qi * 128 + t) * 16;
    float L = 0.f;
    for (int ci = 0; ci <= qi; ++ci) L += lp[ci];
    sRl[t] = 1.0f / L;
  }
  const bf16_t* Ab = P + (size_t)b * SS * SS + (size_t)qi * 128 * SS;
  const bf16_t* Bb = Vt + (size_t)b * DD * SS + (size_t)nj * 128 * SS;
  float* Cb = Out + (size_t)b * SS * DD + (size_t)qi * 128 * DD + nj * 128;
  floatx4 acc[4][4];
  zero_acc(acc);
  mm_core2(Ab, Bb, SS, SS, (qi + 1) * 2, sA0, sB0, sA1, sB1, acc); // K=(qi+1)*128
  const int lane = threadIdx.x & 63;
  const int wm = (threadIdx.x >> 6) >> 1, wn = (threadIdx.x >> 6) & 1;
  const int m0 = wm * 64 + (lane & 15);          // q row
  const int n0 = wn * 64 + (lane >> 4) * 4;      // dv col
#pragma unroll
  for (int i2 = 0; i2 < 4; ++i2) {
    const float scale = sRl[m0 + i2 * 16];
    float* crow = Cb + (size_t)(m0 + i2 * 16) * DD + n0;
#pragma unroll
    for (int j = 0; j < 4; ++j) {
      floatx4 o = acc[i2][j];
      o[0] *= scale; o[1] *= scale; o[2] *= scale; o[3] *= scale;
      *(floatx4*)(crow + j * 16) = o;
    }
  }
}

// ---------------- launch ----------------

extern "C" void kernel_launch(void* const* d_in, const int* in_sizes, int n_in,
                              void* d_out, int out_size, void* d_ws, size_t ws_size,
                              hipStream_t stream) {
  const float* x  = (const float*)d_in[0];
  const float* Wq = (const float*)d_in[1];
  const float* Wk = (const float*)d_in[2];
  const float* Wv = (const float*)d_in[3];
  float* out = (float*)d_out;

  char* ws = (char*)d_ws;
  bf16_t* xb   = (bf16_t*)(ws);                      // 33,554,432  x bf16 [B*S, D]
  bf16_t* Wt   = (bf16_t*)(ws + 33554432ull);        //  6,291,456  Wq^T,Wk^T,Wv^T bf16 [N,K] each
  bf16_t* QKb  = (bf16_t*)(ws + 39845888ull);        // 67,108,864  [Q|K] bf16 [B*S, 2048]
  bf16_t* VtB  = (bf16_t*)(ws + 106954752ull);       // 33,554,432  V^T bf16 [B, D, S]
  bf16_t* Pb   = (bf16_t*)(ws + 140509184ull);       // 67,108,864  P' bf16 [B, S, S] (causal area only)
  float*  lpart= (float*)(ws + 207618048ull);        //  1,048,576  row-sum partials [B*S, 16]
  (void)in_sizes; (void)n_in; (void)out_size; (void)ws_size;

  // 1. convert x + convert/transpose weights (one dispatch)
  prep<<<16384 + 3072, 256, 0, stream>>>(x, Wq, Wk, Wv, xb, Wt);
  // 2. [Q|K] = x @ [Wq|Wk]  (M=16384, N=2048, K=1024), r3 ring-4 core
  qkproj_gemm<<<dim3(64, 8), 512, 0, stream>>>(xb, Wt, QKb);
  // 3. V^T = Wv^T @ x^T, r3 ring-4 core
  vproj_gemm<<<256, 512, 0, stream>>>(xb, Wt, VtB);
  // 4. P' = exp(QK^T/32) on causal tiles + row-sum partials, XCD==batch, ring-2 core
  qk_p<<<1088, 256, 0, stream>>>(QKb, QKb + DD, Pb, lpart);
  // 5. out = (P' @ V) * (1/rowsum), causal K-truncation, XCD==batch, ring-2 core
  pv_gemm<<<1024, 256, 0, stream>>>(Pb, VtB, lpart, out);
}

// Round 8
// 351.103 us; speedup vs baseline: 1.4389x; 1.0001x over previous
//
#include <hip/hip_runtime.h>
#include <hip/hip_bf16.h>
#include <stdint.h>

// DecoderSelfAttention: B=8, S=2048, D=1024 (d_k=d_v=d_model)
// Pipeline (all bf16 MFMA, fp32 accumulate), 4 dispatches:
//   prep:    x->bf16, W->W^T bf16
//   proj:    FUSED [Q|K] = x@[Wq|Wk] (512 blocks) + V^T = Wv^T@x^T (256
//            blocks) -> 768 blocks = 3 perfect rounds at 1 block/CU.
//   qk_p:    P' = exp(QK^T/32) causal tiles + row-sum partials  (XCD==batch)
//   pv:      out = (P' @ V) * 1/rowsum                          (XCD==batch)
//
// Core v7 (both tile sizes): alias-clean ring-4 BK=32 distinct __shared__
// objects (r3-verified), 2-AHEAD staging + counted vmcnt(8) (tail 4/0), and
// ONE barrier per K-tile body.
// Single-barrier race proof:
//   RAW: body T = {stage(T+2); vmcnt(8); BAR_T; reads(T); MFMA}. vmcnt(8)
//        leaves exactly stages T+1,T+2 in flight -> tile T drained by every
//        wave before its BAR_T arrival -> after BAR_T all waves' tile T is
//        in LDS.
//   WAR: wave W's stage(T+2) targets slot (T+2)&3 = (T-2)&3, last read at
//        body T-2. Every wave drains its body-T-2 reads (lgkmcnt(0) before
//        that body's last MFMA cluster) before arriving at BAR_{T-1}; W
//        issues stage(T+2) only after passing BAR_{T-1} (rendezvous) ->
//        no overwrite of in-use data. Wave drift is bounded to one body.
// Swizzle (measured 0 conflicts r1-r7): 32-col K-slab rows of 4 16B-units;
// row r physical unit p holds global unit p ^ ((r>>1)&3) (pre-swizzled
// global source, linear LDS dest for global_load_lds); reader key
// ((fm>>1)&3). Identical formula at both tile sizes.
// r4/r5/r6 lessons kept: no register frag double-buffer (256 reg/wave hard
// cap at 2 waves/SIMD), no BK=64 bodies.

typedef __bf16 bf16_t;
typedef __bf16 bf16x4 __attribute__((ext_vector_type(4)));
typedef __bf16 bf16x8 __attribute__((ext_vector_type(8)));
typedef float  floatx4 __attribute__((ext_vector_type(4)));

#define NB 8
#define SS 2048
#define DD 1024
#define INV_SCALE 0.03125f   // 1/sqrt(1024)

__device__ __forceinline__ void async_ld16(const void* g, void* l) {
  __builtin_amdgcn_global_load_lds(
      (const __attribute__((address_space(1))) void*)g,
      (__attribute__((address_space(3))) void*)l, 16, 0, 0);
}

#define BARRIER() do { asm volatile("" ::: "memory"); \
  __builtin_amdgcn_s_barrier(); asm volatile("" ::: "memory"); } while (0)

// ---------------- 256x256 ring-4 single-barrier GEMM core v7 ----------------
// C = A * B^T, A[M,K] row-major, B[N,K] row-major, both bf16, BK=32.
// 512 thr = 8 waves (2M x 4N), 128x64 per wave, acc[8][4].
// nt = number of 32-wide K steps; REQUIRES nt % 4 == 0, nt >= 4.
__device__ __forceinline__ void mm256_core(
    const bf16_t* __restrict__ Ab, const bf16_t* __restrict__ Bb,
    int lda, int ldb, int nt,
    bf16_t* sA0, bf16_t* sA1, bf16_t* sA2, bf16_t* sA3,
    bf16_t* sB0, bf16_t* sB1, bf16_t* sB2, bf16_t* sB3,
    floatx4 acc[8][4]) {
  const int t    = threadIdx.x;         // 0..511
  const int lane = t & 63;
  const int wid  = t >> 6;
  const int wm   = wid >> 2;            // 0..1
  const int wn   = wid & 3;             // 0..3
  const int fm   = lane & 15;
  const int q    = lane >> 4;           // 0..3 (k-group)
  const int co   = (q ^ ((fm >> 1) & 3)) * 8;   // swizzled k-group offset

  // staging: 2 units/thread/operand; unit u: row=u>>2, src group=(u&3)^((row>>1)&3)
  size_t goA[2], goB[2]; int lo[2];
#pragma unroll
  for (int k = 0; k < 2; ++k) {
    const int u   = k * 512 + t;
    const int row = u >> 2;
    const int cg  = (u & 3) ^ ((row >> 1) & 3);
    goA[k] = (size_t)row * lda + cg * 8;
    goB[k] = (size_t)row * ldb + cg * 8;
    lo[k]  = u * 8;
  }

  auto stage = [&](bf16_t* la, bf16_t* lb, int tile) {
    const size_t ko = (size_t)tile * 32;
    async_ld16(Ab + ko + goA[0], la + lo[0]);
    async_ld16(Ab + ko + goA[1], la + lo[1]);
    async_ld16(Bb + ko + goB[0], lb + lo[0]);
    async_ld16(Bb + ko + goB[1], lb + lo[1]);
  };

  const int paOff = (wm * 128 + fm) * 32;
  const int pbOff = (wn * 64 + fm) * 32;

  // body T: {stage(T+2) into SA/SB; vmcnt(8); BAR; reads(T) from CA/CB; MFMA}
  auto body = [&] __attribute__((always_inline)) (
      const bf16_t* CA, const bf16_t* CB, bf16_t* SA, bf16_t* SB, int T) {
    if (T + 2 < nt) {
      stage(SA, SB, T + 2);
      asm volatile("s_waitcnt vmcnt(8)" ::: "memory");   // tile T landed
    } else if (T + 1 < nt) {
      asm volatile("s_waitcnt vmcnt(4)" ::: "memory");
    } else {
      asm volatile("s_waitcnt vmcnt(0)" ::: "memory");
    }
    BARRIER();                           // single barrier per body

    const bf16_t* pa = CA + paOff;
    const bf16_t* pb = CB + pbOff;
    bf16x8 a0[4], a1[4], bv[4];
#pragma unroll
    for (int i = 0; i < 4; ++i) a0[i] = *(const bf16x8*)(pa + i * 512 + co);
#pragma unroll
    for (int j = 0; j < 4; ++j) bv[j] = *(const bf16x8*)(pb + j * 512 + co);
    __builtin_amdgcn_sched_barrier(0);   // pin group1 (8 reads) before group2
#pragma unroll
    for (int i = 0; i < 4; ++i) a1[i] = *(const bf16x8*)(pa + (4 + i) * 512 + co);

    asm volatile("s_waitcnt lgkmcnt(4)" ::: "memory");   // a0/bv landed
    __builtin_amdgcn_sched_barrier(0);
    __builtin_amdgcn_s_setprio(1);
#pragma unroll
    for (int i = 0; i < 4; ++i)
#pragma unroll
      for (int j = 0; j < 4; ++j)
        acc[i][j] = __builtin_amdgcn_mfma_f32_16x16x32_bf16(bv[j], a0[i], acc[i][j], 0, 0, 0);
    __builtin_amdgcn_s_setprio(0);

    asm volatile("s_waitcnt lgkmcnt(0)" ::: "memory");   // a1 landed
    __builtin_amdgcn_sched_barrier(0);
    __builtin_amdgcn_s_setprio(1);
#pragma unroll
    for (int i = 0; i < 4; ++i)
#pragma unroll
      for (int j = 0; j < 4; ++j)
        acc[4 + i][j] = __builtin_amdgcn_mfma_f32_16x16x32_bf16(bv[j], a1[i], acc[4 + i][j], 0, 0, 0);
    __builtin_amdgcn_s_setprio(0);
  };

  // prologue: 2-ahead
  stage(sA0, sB0, 0);
  stage(sA1, sB1, 1);

  for (int tb = 0; tb < nt; tb += 4) {
    body(sA0, sB0, sA2, sB2, tb + 0);
    body(sA1, sB1, sA3, sB3, tb + 1);
    body(sA2, sB2, sA0, sB0, tb + 2);
    body(sA3, sB3, sA1, sB1, tb + 3);
  }
}

__device__ __forceinline__ void zero_acc8(floatx4 acc[8][4]) {
#pragma unroll
  for (int i = 0; i < 8; ++i)
#pragma unroll
    for (int j = 0; j < 4; ++j)
      acc[i][j] = floatx4{0.f, 0.f, 0.f, 0.f};
}

__device__ __forceinline__ void store_c256_bf16(bf16_t* __restrict__ Cb, int ldc,
                                                floatx4 acc[8][4]) {
  const int lane = threadIdx.x & 63;
  const int wid  = threadIdx.x >> 6;
  const int wm = wid >> 2, wn = wid & 3;
  const int m0 = wm * 128 + (lane & 15);
  const int n0 = wn * 64 + (lane >> 4) * 4;
#pragma unroll
  for (int i = 0; i < 8; ++i)
#pragma unroll
    for (int j = 0; j < 4; ++j) {
      floatx4 a = acc[i][j];
      bf16x4 o = {(bf16_t)a[0], (bf16_t)a[1], (bf16_t)a[2], (bf16_t)a[3]};
      *(bf16x4*)(Cb + (size_t)(m0 + i * 16) * ldc + n0 + j * 16) = o;
    }
}

#define MM256_LDS_DECL                                                      \
  __shared__ __attribute__((aligned(16))) bf16_t sA0[8192], sA1[8192],      \
      sA2[8192], sA3[8192];                                                 \
  __shared__ __attribute__((aligned(16))) bf16_t sB0[8192], sB1[8192],      \
      sB2[8192], sB3[8192];

// ---------------- 128x128 ring-4 single-barrier GEMM core v7 ----------------
// C = A * B^T, bf16, BK=32, 256 thr (4 waves 2x2), 64x64/wave, acc[4][4].
// nt = number of 32-wide K steps; REQUIRES nt % 4 == 0, nt >= 4.
// Slots are [128 rows][32 cols] = 8KB each; 8 distinct arrays = 64KB total.
// NOTE: body uses lgkmcnt(0) only -> also drains any pre-core ds_writes
// (pv's sRl) before MFMA, so prologue LDS writes are safe.
__device__ __forceinline__ void mm128_core(
    const bf16_t* __restrict__ Ab, const bf16_t* __restrict__ Bb,
    int lda, int ldb, int nt,
    bf16_t* sA0, bf16_t* sA1, bf16_t* sA2, bf16_t* sA3,
    bf16_t* sB0, bf16_t* sB1, bf16_t* sB2, bf16_t* sB3,
    floatx4 acc[4][4]) {
  const int t    = threadIdx.x;         // 0..255
  const int lane = t & 63;
  const int wm   = (t >> 6) >> 1;       // 0..1
  const int wn   = (t >> 6) & 1;        // 0..1
  const int fm   = lane & 15;
  const int q    = lane >> 4;           // 0..3
  const int co   = (q ^ ((fm >> 1) & 3)) * 8;

  // staging: 2 units/thread/operand; unit u: row=u>>2, src unit=(u&3)^((row>>1)&3)
  size_t goA[2], goB[2]; int lo[2];
#pragma unroll
  for (int k = 0; k < 2; ++k) {
    const int u   = k * 256 + t;
    const int row = u >> 2;
    const int cg  = (u & 3) ^ ((row >> 1) & 3);
    goA[k] = (size_t)row * lda + cg * 8;
    goB[k] = (size_t)row * ldb + cg * 8;
    lo[k]  = u * 8;
  }

  auto stage = [&](bf16_t* la, bf16_t* lb, int tile) {
    const size_t ko = (size_t)tile * 32;
    async_ld16(Ab + ko + goA[0], la + lo[0]);
    async_ld16(Ab + ko + goA[1], la + lo[1]);
    async_ld16(Bb + ko + goB[0], lb + lo[0]);
    async_ld16(Bb + ko + goB[1], lb + lo[1]);
  };

  const int paOff = (wm * 64 + fm) * 32;
  const int pbOff = (wn * 64 + fm) * 32;

  auto body = [&] __attribute__((always_inline)) (
      const bf16_t* CA, const bf16_t* CB, bf16_t* SA, bf16_t* SB, int T) {
    if (T + 2 < nt) {
      stage(SA, SB, T + 2);
      asm volatile("s_waitcnt vmcnt(8)" ::: "memory");   // tile T landed
    } else if (T + 1 < nt) {
      asm volatile("s_waitcnt vmcnt(4)" ::: "memory");
    } else {
      asm volatile("s_waitcnt vmcnt(0)" ::: "memory");
    }
    BARRIER();

    const bf16_t* pa = CA + paOff;
    const bf16_t* pb = CB + pbOff;
    bf16x8 af[4], bv[4];
#pragma unroll
    for (int i = 0; i < 4; ++i) af[i] = *(const bf16x8*)(pa + i * 512 + co);
#pragma unroll
    for (int j = 0; j < 4; ++j) bv[j] = *(const bf16x8*)(pb + j * 512 + co);
    asm volatile("s_waitcnt lgkmcnt(0)" ::: "memory");
    __builtin_amdgcn_sched_barrier(0);
    __builtin_amdgcn_s_setprio(1);
#pragma unroll
    for (int i = 0; i < 4; ++i)
#pragma unroll
      for (int j = 0; j < 4; ++j)
        acc[i][j] = __builtin_amdgcn_mfma_f32_16x16x32_bf16(bv[j], af[i], acc[i][j], 0, 0, 0);
    __builtin_amdgcn_s_setprio(0);
  };

  stage(sA0, sB0, 0);
  stage(sA1, sB1, 1);
  for (int tb = 0; tb < nt; tb += 4) {
    body(sA0, sB0, sA2, sB2, tb + 0);
    body(sA1, sB1, sA3, sB3, tb + 1);
    body(sA2, sB2, sA0, sB0, tb + 2);
    body(sA3, sB3, sA1, sB1, tb + 3);
  }
}

__device__ __forceinline__ void zero_acc(floatx4 acc[4][4]) {
#pragma unroll
  for (int i = 0; i < 4; ++i)
#pragma unroll
    for (int j = 0; j < 4; ++j)
      acc[i][j] = floatx4{0.f, 0.f, 0.f, 0.f};
}

#define MM128_LDS_DECL                                                      \
  __shared__ __attribute__((aligned(16))) bf16_t sA0[4096], sA1[4096],      \
      sA2[4096], sA3[4096];                                                 \
  __shared__ __attribute__((aligned(16))) bf16_t sB0[4096], sB1[4096],      \
      sB2[4096], sB3[4096];

// ---------------- fused converters: x->bf16 and W->W^T bf16 ----------------

__global__ __launch_bounds__(256) void prep(const float* __restrict__ x,
                                            const float* __restrict__ Wq,
                                            const float* __restrict__ Wk,
                                            const float* __restrict__ Wv,
                                            bf16_t* __restrict__ xb,
                                            bf16_t* __restrict__ Wt) {
  __shared__ float tile[32][33];
  const int bid = blockIdx.x;
  const int t = threadIdx.x;
  if (bid < 16384) {
    size_t i = (size_t)bid * 256 + t;
    float4 v = ((const float4*)x)[i];
    bf16x4 o = {(bf16_t)v.x, (bf16_t)v.y, (bf16_t)v.z, (bf16_t)v.w};
    ((bf16x4*)xb)[i] = o;
  } else {
    const int wb = bid - 16384;
    const int z = wb >> 10;                 // 0,1,2 -> Wq,Wk,Wv
    const int rem = wb & 1023;
    const float* W = (z == 0) ? Wq : (z == 1 ? Wk : Wv);
    bf16_t* O = Wt + (size_t)z * DD * DD;
    const int ty = t >> 3;
    const int tx = t & 7;
    const int k0 = (rem >> 5) * 32, n0 = (rem & 31) * 32;
    float4 v = *(const float4*)(W + (size_t)(k0 + ty) * DD + n0 + tx * 4);
    tile[ty][tx * 4 + 0] = v.x;
    tile[ty][tx * 4 + 1] = v.y;
    tile[ty][tx * 4 + 2] = v.z;
    tile[ty][tx * 4 + 3] = v.w;
    __syncthreads();
    bf16x4 o = {(bf16_t)tile[tx * 4 + 0][ty], (bf16_t)tile[tx * 4 + 1][ty],
                (bf16_t)tile[tx * 4 + 2][ty], (bf16_t)tile[tx * 4 + 3][ty]};
    *(bf16x4*)(O + (size_t)(n0 + ty) * DD + k0 + tx * 4) = o;
  }
}

// ---------------- FUSED projections ----------------
// bids 0..511:   [Q|K] tile (mt = bid&63 fastest, nt = bid>>6) -> QKb
// bids 512..767: V^T tile (r = bid-512: n=r&7 (XCD), m=(r>>3)&3, b=r>>5) -> VtB
// ldc = 2048 for both outputs; lda = ldb = DD; nt = 32. Hot path uniform.

__global__ __launch_bounds__(512, 2) void proj_gemm(
    const bf16_t* __restrict__ xb, const bf16_t* __restrict__ Wt,
    bf16_t* __restrict__ QKb, bf16_t* __restrict__ VtB) {
  MM256_LDS_DECL
  const int bid = blockIdx.x;
  const bf16_t* Ab;
  const bf16_t* Bb;
  bf16_t* Cb;
  if (bid < 512) {
    const int mt = bid & 63, nt2 = bid >> 6;
    Ab = xb + (size_t)mt * 256 * DD;
    Bb = Wt + (size_t)nt2 * 256 * DD;
    Cb = QKb + (size_t)mt * 256 * (2 * DD) + nt2 * 256;
  } else {
    const int r = bid - 512;
    const int n = r & 7;            // seq tile (XCD)
    const int m = (r >> 3) & 3;     // dv tile
    const int b = r >> 5;           // batch
    Ab = Wt + (size_t)2 * DD * DD + (size_t)m * 256 * DD;
    Bb = xb + (size_t)b * SS * DD + (size_t)n * 256 * DD;
    Cb = VtB + (size_t)b * DD * SS + (size_t)m * 256 * SS + n * 256;
  }
  floatx4 acc[8][4];
  zero_acc8(acc);
  mm256_core(Ab, Bb, DD, DD, DD / 32,
             sA0, sA1, sA2, sA3, sB0, sB1, sB2, sB3, acc);
  store_c256_bf16(Cb, 2048, acc);
}

// ---------------- QK^T -> P' = exp(s) bf16 (causal tiles only) + row-sum partials ----------------
// 1D grid 1088: b = bid&7 (XCD==batch), tt = 135-(bid>>3) (qi descending).

__global__ __launch_bounds__(256) void qk_p(
    const bf16_t* __restrict__ Q, const bf16_t* __restrict__ K,
    bf16_t* __restrict__ P, float* __restrict__ lpart) {
  const int b  = blockIdx.x & 7;
  const int tt = 135 - (blockIdx.x >> 3);
  int qi = (int)((sqrtf(8.0f * tt + 1.0f) - 1.0f) * 0.5f);
  while ((qi + 1) * (qi + 2) / 2 <= tt) ++qi;
  while (qi * (qi + 1) / 2 > tt) --qi;
  const int ki = tt - qi * (qi + 1) / 2;

  MM128_LDS_DECL
  __shared__ float reds[2][128];
  const bf16_t* Ab = Q + ((size_t)b * SS + qi * 128) * (size_t)(2 * DD);
  const bf16_t* Bb = K + ((size_t)b * SS + ki * 128) * (size_t)(2 * DD);
  floatx4 acc[4][4];
  zero_acc(acc);
  mm128_core(Ab, Bb, 2 * DD, 2 * DD, DD / 32,
             sA0, sA1, sA2, sA3, sB0, sB1, sB2, sB3, acc);

  const int lane = threadIdx.x & 63;
  const int wm = (threadIdx.x >> 6) >> 1, wn = (threadIdx.x >> 6) & 1;
  const bool diag = (ki == qi);
  bf16_t* Pb = P + (size_t)b * SS * SS;
  const int qloc0 = wm * 64 + (lane & 15);        // + i*16
  const int kvb0  = wn * 64 + (lane >> 4) * 4;    // + j*16, + reg

#pragma unroll
  for (int i = 0; i < 4; ++i) {
    const int qrow = qloc0 + i * 16;
    float partial = 0.f;
#pragma unroll
    for (int j = 0; j < 4; ++j) {
      const int kvb = kvb0 + j * 16;
      floatx4 p;
#pragma unroll
      for (int r = 0; r < 4; ++r) {
        const float s = acc[i][j][r] * INV_SCALE;
        p[r] = (diag && (kvb + r) > qrow) ? 0.f : __expf(s);
        partial += p[r];
      }
      bf16x4 o = {(bf16_t)p[0], (bf16_t)p[1], (bf16_t)p[2], (bf16_t)p[3]};
      *(bf16x4*)(Pb + (size_t)(qi * 128 + qrow) * SS + ki * 128 + kvb) = o;
    }
    partial += __shfl_xor(partial, 16);
    partial += __shfl_xor(partial, 32);
    if ((lane >> 4) == 0) reds[wn][qrow] = partial;
  }
  __syncthreads();
  const int t = threadIdx.x;
  if (t < 128) {
    size_t row = (size_t)b * SS + qi * 128 + t;
    lpart[row * 16 + ki] = reds[0][t] + reds[1][t];
  }
}

// ---------------- PV GEMM (causal-truncated K-loop), rowsum+scale folded, fp32 out ----------------
// 1D grid 1024: b = bid&7 (XCD==batch), nj = (bid>>3)&7, qi = 15-(bid>>6) desc.

__global__ __launch_bounds__(256) void pv_gemm(
    const bf16_t* __restrict__ P, const bf16_t* __restrict__ Vt,
    const float* __restrict__ lpart, float* __restrict__ Out) {
  const int bid = blockIdx.x;
  const int b  = bid & 7;
  const int nj = (bid >> 3) & 7;
  const int qi = 15 - (bid >> 6);

  MM128_LDS_DECL
  __shared__ float sRl[128];
  const int t = threadIdx.x;
  if (t < 128) {
    const float* lp = lpart + ((size_t)b * SS + qi * 128 + t) * 16;
    float L = 0.f;
    for (int ci = 0; ci <= qi; ++ci) L += lp[ci];
    sRl[t] = 1.0f / L;
  }
  const bf16_t* Ab = P + (size_t)b * SS * SS + (size_t)qi * 128 * SS;
  const bf16_t* Bb = Vt + (size_t)b * DD * SS + (size_t)nj * 128 * SS;
  float* Cb = Out + (size_t)b * SS * DD + (size_t)qi * 128 * DD + nj * 128;
  floatx4 acc[4][4];
  zero_acc(acc);
  mm128_core(Ab, Bb, SS, SS, (qi + 1) * 4,
             sA0, sA1, sA2, sA3, sB0, sB1, sB2, sB3, acc);  // K=(qi+1)*128
  const int lane = threadIdx.x & 63;
  const int wm = (threadIdx.x >> 6) >> 1, wn = (threadIdx.x >> 6) & 1;
  const int m0 = wm * 64 + (lane & 15);          // q row
  const int n0 = wn * 64 + (lane >> 4) * 4;      // dv col
#pragma unroll
  for (int i2 = 0; i2 < 4; ++i2) {
    const float scale = sRl[m0 + i2 * 16];
    float* crow = Cb + (size_t)(m0 + i2 * 16) * DD + n0;
#pragma unroll
    for (int j = 0; j < 4; ++j) {
      floatx4 o = acc[i2][j];
      o[0] *= scale; o[1] *= scale; o[2] *= scale; o[3] *= scale;
      *(floatx4*)(crow + j * 16) = o;
    }
  }
}

// ---------------- launch ----------------

extern "C" void kernel_launch(void* const* d_in, const int* in_sizes, int n_in,
                              void* d_out, int out_size, void* d_ws, size_t ws_size,
                              hipStream_t stream) {
  const float* x  = (const float*)d_in[0];
  const float* Wq = (const float*)d_in[1];
  const float* Wk = (const float*)d_in[2];
  const float* Wv = (const float*)d_in[3];
  float* out = (float*)d_out;

  char* ws = (char*)d_ws;
  bf16_t* xb   = (bf16_t*)(ws);                      // 33,554,432  x bf16 [B*S, D]
  bf16_t* Wt   = (bf16_t*)(ws + 33554432ull);        //  6,291,456  Wq^T,Wk^T,Wv^T bf16 [N,K] each
  bf16_t* QKb  = (bf16_t*)(ws + 39845888ull);        // 67,108,864  [Q|K] bf16 [B*S, 2048]
  bf16_t* VtB  = (bf16_t*)(ws + 106954752ull);       // 33,554,432  V^T bf16 [B, D, S]
  bf16_t* Pb   = (bf16_t*)(ws + 140509184ull);       // 67,108,864  P' bf16 [B, S, S] (causal area only)
  float*  lpart= (float*)(ws + 207618048ull);        //  1,048,576  row-sum partials [B*S, 16]
  (void)in_sizes; (void)n_in; (void)out_size; (void)ws_size;

  // 1. convert x + convert/transpose weights (one dispatch)
  prep<<<16384 + 3072, 256, 0, stream>>>(x, Wq, Wk, Wv, xb, Wt);
  // 2. FUSED: [Q|K] = x @ [Wq|Wk] (512 blocks) + V^T = Wv^T@x^T (256 blocks)
  proj_gemm<<<768, 512, 0, stream>>>(xb, Wt, QKb, VtB);
  // 3. P' = exp(QK^T/32) on causal tiles + row-sum partials, XCD==batch
  qk_p<<<1088, 256, 0, stream>>>(QKb, QKb + DD, Pb, lpart);
  // 4. out = (P' @ V) * (1/rowsum), causal K-truncation, XCD==batch, nj inner
  pv_gemm<<<1024, 256, 0, stream>>>(Pb, VtB, lpart, out);
}